// Round 14
// baseline (350.570 us; speedup 1.0000x reference)
//
#include <hip/hip_runtime.h>
#include <hip/hip_bf16.h>

#define DM 512
#define DH 64
#define NH 8
#define NP 2048
#define NB 2
#define NROWS (NB*NP)
#define JC1 8            // attn1 j-chunks (chunk = 256 j, 16 jt of 16)
#define JC2 8            // attn2 j-chunks (chunk = 256 j, 16 jt of 16)
#define NT1 (NP/JC1/16)  // 16
#define NT2 (NP/JC2/16)  // 16
#define OPITCH 520       // LDS pitch (shorts) for 512-wide tiles
#define SPITCH 136       // LDS pitch (shorts) for 128-wide slab (attn2p epilogue)

typedef short s16x8 __attribute__((ext_vector_type(8)));
typedef short s16x4 __attribute__((ext_vector_type(4)));
typedef float f32x4 __attribute__((ext_vector_type(4)));
typedef unsigned int u32x4 __attribute__((ext_vector_type(4)));
typedef unsigned int u32x2 __attribute__((ext_vector_type(2)));

__device__ __forceinline__ unsigned short f2bf(float f){
  __hip_bfloat16 h = __float2bfloat16(f);
  return __builtin_bit_cast(unsigned short, h);
}

__device__ __forceinline__ f32x4 mfma16(s16x8 a, s16x8 b, f32x4 c){
  return __builtin_amdgcn_mfma_f32_16x16x32_bf16(a, b, c, 0, 0, 0);
}

__device__ __forceinline__ f32x4 mfma16k16(s16x4 a, s16x4 b, f32x4 c){
#if __has_builtin(__builtin_amdgcn_mfma_f32_16x16x16bf16_1k)
  return __builtin_amdgcn_mfma_f32_16x16x16bf16_1k(a, b, c, 0, 0, 0);
#else
  asm volatile("v_mfma_f32_16x16x16_bf16 %0, %1, %2, %0\n\ts_nop 7\n\ts_nop 7"
               : "+v"(c) : "v"(a), "v"(b));
  return c;
#endif
}

__device__ __forceinline__ s16x4 pack4(f32x4 a){
  u32x2 u;
  u.x = (unsigned)f2bf(a[0]) | ((unsigned)f2bf(a[1])<<16);
  u.y = (unsigned)f2bf(a[2]) | ((unsigned)f2bf(a[3])<<16);
  return __builtin_bit_cast(s16x4, u);
}

// ---------------- prep: x fp32 -> bf16 ----------------
__global__ void prep_x(const float* __restrict__ x, unsigned short* __restrict__ xb){
  int i = (blockIdx.x*256 + threadIdx.x)*4;
  float4 v = *(const float4*)(x + i);
  unsigned short s0=f2bf(v.x), s1=f2bf(v.y), s2=f2bf(v.z), s3=f2bf(v.w);
  uint2 u; u.x = (unsigned)s0 | ((unsigned)s1<<16); u.y = (unsigned)s2 | ((unsigned)s3<<16);
  *(uint2*)(xb + i) = u;
}

// ---------------- prep: transpose weights to [n][k] bf16 ----------------
__global__ void prep_w(const float* __restrict__ Wq, const float* __restrict__ Wk,
                       const float* __restrict__ Wv, const float* __restrict__ Wp,
                       unsigned short* __restrict__ WT){
  __shared__ float t[64][65];
  const float* W = (blockIdx.z==0)?Wq:(blockIdx.z==1)?Wk:(blockIdx.z==2)?Wv:Wp;
  const int k0 = blockIdx.x*64, n0 = blockIdx.y*64;
  const int c = threadIdx.x&63, rq = threadIdx.x>>6;
  #pragma unroll
  for(int rr=0;rr<16;rr++){
    int kl = rq*16+rr;
    t[kl][c] = W[(size_t)(k0+kl)*DM + n0 + c];
  }
  __syncthreads();
  unsigned short* o = WT + (size_t)blockIdx.z*DM*DM;
  #pragma unroll
  for(int rr=0;rr<16;rr++){
    int nl = rq*16+rr;
    o[(size_t)(n0+nl)*DM + k0 + c] = f2bf(t[c][nl]);
  }
}

// ---------------- QKV projection GEMM ----------------
// z=0: Qs (scaled 1/8) [b][h][p][d]; z=1: K [b][h][p][d];
// z=2: VA — V^T in K16-A-frag-native layout [b][g][nt][p/4][d&15][p&3]
__global__ __launch_bounds__(256) void qkv_kern(const unsigned short* __restrict__ xb,
    const unsigned short* __restrict__ WT,
    unsigned short* __restrict__ Qs, unsigned short* __restrict__ Kk,
    unsigned short* __restrict__ VA){
  const int z = blockIdx.z, h = blockIdx.y;
  const int R0 = blockIdx.x*64;
  const int tid = threadIdx.x;
  const int w = tid>>6, lane = tid&63, m = lane&15, q = lane>>4;
  const unsigned short* Wz = WT + (size_t)z*DM*DM;
  f32x4 acc[4] = {};
  const unsigned short* arow = xb + (size_t)(R0 + w*16 + m)*DM + q*8;
  const unsigned short* brow = Wz + (size_t)(h*64 + m)*DM + q*8;
  for(int k=0;k<DM;k+=32){
    s16x8 A = *(const s16x8*)(arow + k);
    #pragma unroll
    for(int nt=0;nt<4;nt++){
      s16x8 B = *(const s16x8*)(brow + (size_t)nt*16*DM + k);
      acc[nt] = mfma16(A, B, acc[nt]);
    }
  }
  __shared__ float t[64][65];
  const float scale = (z==0) ? 0.125f : 1.0f;
  #pragma unroll
  for(int nt=0;nt<4;nt++)
    #pragma unroll
    for(int r=0;r<4;r++)
      t[w*16 + q*4 + r][nt*16 + m] = acc[nt][r]*scale;
  __syncthreads();
  const int b = R0>>11, p0 = R0&2047;
  if(z<2){
    unsigned short* outp = (z==0)? Qs : Kk;
    int pl = tid>>2, c0 = (tid&3)*16;
    unsigned short vbuf[16];
    #pragma unroll
    for(int i=0;i<16;i++) vbuf[i]=f2bf(t[pl][c0+i]);
    unsigned short* dst = outp + ((size_t)(b*NH+h)*NP + p0+pl)*DH + c0;
    uint4 u0, u1;
    u0.x=(unsigned)vbuf[0]|((unsigned)vbuf[1]<<16);  u0.y=(unsigned)vbuf[2]|((unsigned)vbuf[3]<<16);
    u0.z=(unsigned)vbuf[4]|((unsigned)vbuf[5]<<16);  u0.w=(unsigned)vbuf[6]|((unsigned)vbuf[7]<<16);
    u1.x=(unsigned)vbuf[8]|((unsigned)vbuf[9]<<16);  u1.y=(unsigned)vbuf[10]|((unsigned)vbuf[11]<<16);
    u1.z=(unsigned)vbuf[12]|((unsigned)vbuf[13]<<16);u1.w=(unsigned)vbuf[14]|((unsigned)vbuf[15]<<16);
    *(uint4*)dst = u0; *(uint4*)(dst+8) = u1;
  } else {
    int d = tid>>2, c0 = (tid&3)*16;
    unsigned short* vb = VA + (size_t)b*(8u*4u*(NP/4)*64u)
        + ((size_t)(h*4 + (d>>4))*(NP/4))*64 + (size_t)(d&15)*4;
    #pragma unroll
    for(int grp=0; grp<4; grp++){
      int pl = c0 + grp*4;
      unsigned short v4[4];
      #pragma unroll
      for(int tt=0; tt<4; tt++) v4[tt] = f2bf(t[pl+tt][d]);
      uint2 u; u.x = (unsigned)v4[0] | ((unsigned)v4[1]<<16);
      u.y = (unsigned)v4[2] | ((unsigned)v4[3]<<16);
      *(uint2*)(vb + (size_t)((p0 + pl)>>2)*64) = u;
    }
  }
}

// ---------------- attn sweep 1 (fallback): denominators only --------------
// DO NOT peephole the attn inner loops: r1/r2 showed any perturbation of the
// instruction stream tips the 256-reg knife edge into scratch spills.
// NOTE (r11): fusing the two sweeps is mathematically INVALID — the W2 mix
// couples P-head h with V-head go; two sweeps (or P materialization) forced.
__global__ __launch_bounds__(128,2) void attn1_kern(const unsigned short* __restrict__ Qs,
    const unsigned short* __restrict__ Kk, const float* __restrict__ W1,
    float* __restrict__ Lpart){
  const int bx = blockIdx.x;
  const int c = bx & 7;
  const int b = (bx>>3) & 1;
  const int it = bx>>4;                  // 0..63
  const int tid = threadIdx.x;
  const int iw = tid>>6, lane = tid&63, m = lane&15, q = lane>>4;
  const int i0 = it*32 + iw*16;
  const int cb = c*(NP/JC1);

  float w1[8][8];
  #pragma unroll
  for(int h=0;h<8;h++)
    #pragma unroll
    for(int g=0;g<8;g++) w1[h][g]=W1[h*8+g];

  const unsigned short* Qb = Qs + (size_t)b*NH*NP*DH;
  const unsigned short* Kb = Kk + (size_t)b*NH*NP*DH;

  s16x8 Qf[8][2];
  #pragma unroll
  for(int h=0;h<8;h++){
    const unsigned short* qp = Qb + ((size_t)h*NP + i0 + m)*DH + q*8;
    Qf[h][0] = *(const s16x8*)(qp);
    Qf[h][1] = *(const s16x8*)(qp + 32);
  }

  float lacc[8] = {};
  for(int jt=0; jt<NT1; jt++){
    const int j0 = cb + jt*16;
    s16x8 K[8][2];
    #pragma unroll
    for(int h=0;h<8;h++){
      const unsigned short* kp = Kb + ((size_t)h*NP + j0 + m)*DH + q*8;
      K[h][0] = *(const s16x8*)(kp);
      K[h][1] = *(const s16x8*)(kp + 32);
    }
    f32x4 s1[8] = {};
    #pragma unroll
    for(int h=0;h<8;h++){
      f32x4 z = {};
      z = mfma16(K[h][0], Qf[h][0], z);       // A=K (m=j), B=Q (n=i) -> S^T
      f32x4 Sh = mfma16(K[h][1], Qf[h][1], z);
      #pragma unroll
      for(int g=0;g<8;g++) s1[g] += Sh*w1[h][g];
    }
    #pragma unroll
    for(int g=0;g<8;g++)
      #pragma unroll
      for(int r=0;r<4;r++) lacc[g] += __expf(s1[g][r]);
  }
  #pragma unroll
  for(int g=0;g<8;g++){
    float v = lacc[g];
    v += __shfl_xor(v,16); v += __shfl_xor(v,32);
    lacc[g] = v;
  }
  if(lane < 16){
    #pragma unroll
    for(int g=0;g<8;g++)
      Lpart[(((size_t)c*NB + b)*NH + g)*NP + i0 + lane] = lacc[g];
  }
}

// ---------------- attn sweep 1 (P-store, per-h K-rotated) -----------------
// r10 verified best: full 8 heads, grid 1024, live-set-neutral K rotation —
// K[h] reloaded in place with jt+1's tile immediately after its two MFMAs
// consume it. Each K load gets ~7/8 of the h-loop + exp/pack tail of cover.
__global__ __launch_bounds__(128,2) void attn1p_kern(const unsigned short* __restrict__ Qs,
    const unsigned short* __restrict__ Kk, const float* __restrict__ W1,
    float* __restrict__ Lpart, unsigned short* __restrict__ Pm){
  const int bx = blockIdx.x;
  const int c = bx & 7;
  const int b = (bx>>3) & 1;
  const int it = bx>>4;                  // 0..63
  const int tid = threadIdx.x;
  const int iw = tid>>6, lane = tid&63, m = lane&15, q = lane>>4;
  const int i0 = it*32 + iw*16;
  const int cb = c*(NP/JC1);

  float w1[8][8];
  #pragma unroll
  for(int h=0;h<8;h++)
    #pragma unroll
    for(int g=0;g<8;g++) w1[h][g]=W1[h*8+g];

  const unsigned short* Qb = Qs + (size_t)b*NH*NP*DH;
  const unsigned short* Kb = Kk + (size_t)b*NH*NP*DH;
  unsigned short* Pw = Pm + (((size_t)bx*2 + iw)*16)*8*64*4;

  s16x8 Qf[8][2];
  #pragma unroll
  for(int h=0;h<8;h++){
    const unsigned short* qp = Qb + ((size_t)h*NP + i0 + m)*DH + q*8;
    Qf[h][0] = *(const s16x8*)(qp);
    Qf[h][1] = *(const s16x8*)(qp + 32);
  }

  // preload K tile for jt=0
  s16x8 K[8][2];
  #pragma unroll
  for(int h=0;h<8;h++){
    const unsigned short* kp = Kb + ((size_t)h*NP + cb + m)*DH + q*8;
    K[h][0] = *(const s16x8*)(kp);
    K[h][1] = *(const s16x8*)(kp + 32);
  }

  float lacc[8] = {};
  for(int jt=0; jt<NT1; jt++){
    const int j1 = cb + (jt+1)*16;
    f32x4 s1[8] = {};
    #pragma unroll
    for(int h=0;h<8;h++){
      f32x4 z = {};
      z = mfma16(K[h][0], Qf[h][0], z);       // A=K (m=j), B=Q (n=i) -> S^T
      f32x4 Sh = mfma16(K[h][1], Qf[h][1], z);
      // K[h] dead now: reload in place with next jt's tile
      if(jt+1 < NT1){
        const unsigned short* kp = Kb + ((size_t)h*NP + j1 + m)*DH + q*8;
        K[h][0] = *(const s16x8*)(kp);
        K[h][1] = *(const s16x8*)(kp + 32);
      }
      #pragma unroll
      for(int g=0;g<8;g++) s1[g] += Sh*w1[h][g];
    }
    unsigned short* Pjt = Pw + (size_t)jt*8*64*4;
    #pragma unroll
    for(int g=0;g<8;g++){
      f32x4 e;
      #pragma unroll
      for(int r=0;r<4;r++){ e[r] = __expf(s1[g][r]); lacc[g] += e[r]; }
      s16x4 pk = pack4(e);
      __builtin_nontemporal_store(pk, (s16x4*)(Pjt + ((size_t)g*64 + lane)*4));
    }
  }
  #pragma unroll
  for(int g=0;g<8;g++){
    float v = lacc[g];
    v += __shfl_xor(v,16); v += __shfl_xor(v,32);
    lacc[g] = v;
  }
  if(lane < 16){
    #pragma unroll
    for(int g=0;g<8;g++)
      Lpart[(((size_t)c*NB + b)*NH + g)*NP + i0 + lane] = lacc[g];
  }
}

// ---------------- attn sweep 2 (fallback): full recompute -----------------
__global__ __launch_bounds__(128,2) void attn2_kern(const unsigned short* __restrict__ Qs,
    const unsigned short* __restrict__ Kk, const unsigned short* __restrict__ VA,
    const float* __restrict__ W1, const float* __restrict__ W2,
    const float* __restrict__ Lpart, unsigned short* __restrict__ Opart){
  const int bx = blockIdx.x;
  const int c = bx & 7;
  const int b = (bx>>3) & 1;
  const int it = bx>>4;
  const int tid = threadIdx.x;
  const int iw = tid>>6, lane = tid&63, m = lane&15, q = lane>>4;
  const int i0 = it*32 + iw*16;
  const int cb = c*(NP/JC2);

  __shared__ unsigned short Osh[32*OPITCH];

  float w1[8][8], w2[8][8];
  #pragma unroll
  for(int h=0;h<8;h++)
    #pragma unroll
    for(int g=0;g<8;g++){ w1[h][g]=W1[h*8+g]; w2[h][g]=W2[h*8+g]; }

  const unsigned short* Qb = Qs + (size_t)b*NH*NP*DH;
  const unsigned short* Kb = Kk + (size_t)b*NH*NP*DH;
  const unsigned short* VAb = VA + (size_t)b*(8u*4u*(NP/4)*64u);

  {
    const int qr = lane>>2, qc = (lane&3)*16;
    #pragma unroll
    for(int h=0;h<8;h++){
      const unsigned short* src = Qb + ((size_t)h*NP + i0 + qr)*DH + qc;
      unsigned short* dst = &Osh[(size_t)(iw*16+qr)*OPITCH + h*64 + qc];
      *(u32x4*)dst = *(const u32x4*)src;
      *(u32x4*)(dst+8) = *(const u32x4*)(src+8);
    }
  }

  float rl[8];
  #pragma unroll
  for(int g=0;g<8;g++){
    float v = 0.f;
    #pragma unroll
    for(int cc=0;cc<JC1;cc++)
      v += Lpart[(((size_t)cc*NB + b)*NH + g)*NP + i0 + m];
    rl[g] = 1.0f/v;
  }

  f32x4 Oacc[8][4] = {};
  const unsigned short* QL = &Osh[(size_t)(iw*16+m)*OPITCH];

  for(int jt=0; jt<NT2; jt++){
    const int j0 = cb + jt*16;
    s16x8 K[8][2];
    #pragma unroll
    for(int h=0;h<8;h++){
      const unsigned short* kp = Kb + ((size_t)h*NP + j0 + m)*DH + q*8;
      K[h][0] = *(const s16x8*)(kp);
      K[h][1] = *(const s16x8*)(kp + 32);
    }
    f32x4 s1[8] = {};
    #pragma unroll
    for(int h=0;h<8;h++){
      s16x8 q0 = *(const s16x8*)(QL + h*64 + q*8);
      s16x8 q1 = *(const s16x8*)(QL + h*64 + 32 + q*8);
      f32x4 z = {};
      z = mfma16(K[h][0], q0, z);
      f32x4 Sh = mfma16(K[h][1], q1, z);
      #pragma unroll
      for(int g=0;g<8;g++) s1[g] += Sh*w1[h][g];
    }
    s16x4 Vf[8][4];
    const size_t jq = (size_t)(j0>>2) + q;
    #pragma unroll
    for(int g=0;g<8;g++)
      #pragma unroll
      for(int nt=0;nt<4;nt++)
        Vf[g][nt] = *(const s16x4*)(VAb + ((((size_t)g*4+nt)*(NP/4) + jq)<<6) + (m<<2));
    #pragma unroll
    for(int g=0;g<8;g++){
      #pragma unroll
      for(int r=0;r<4;r++) s1[g][r] = __expf(s1[g][r]);
      s1[g] *= rl[g];
    }
    s16x4 A2[8];
    #pragma unroll
    for(int go=0;go<8;go++){
      f32x4 a = s1[0]*w2[0][go];
      #pragma unroll
      for(int h=1;h<8;h++) a += s1[h]*w2[h][go];
      A2[go] = pack4(a);
    }
    #pragma unroll
    for(int g=0;g<8;g++)
      #pragma unroll
      for(int nt=0;nt<4;nt++)
        Oacc[g][nt] = mfma16k16(Vf[g][nt], A2[g], Oacc[g][nt]);
  }

  #pragma unroll
  for(int g=0;g<8;g++)
    #pragma unroll
    for(int nt=0;nt<4;nt++){
      s16x4 pk = pack4(Oacc[g][nt]);
      *(s16x4*)(&Osh[(size_t)(iw*16 + m)*OPITCH + g*64 + nt*16 + 4*q]) = pk;
    }
  __syncthreads();
  unsigned short* Oc = Opart + (size_t)c*NROWS*DM;
  const size_t R0 = (size_t)b*NP + (size_t)it*32;
  #pragma unroll
  for(int t=0;t<16;t++){
    int idx = t*128 + tid;
    int row = idx>>6, c8 = idx&63;
    u32x4 v = *(const u32x4*)(&Osh[(size_t)row*OPITCH + c8*8]);
    __builtin_nontemporal_store(v, (u32x4*)(Oc + (R0 + row)*DM + c8*8));
  }
}

// ---------------- attn sweep 2 (P-load, go-quarter, sibling-adjacent) -----
// r14: keep r13's 4-waves/SIMD bucket (96->112 unified <=128) but fix its
// two measured losses: (1) go0 moves to the FASTEST blockIdx.x bits so the
// 4 siblings sharing a Pw slice dispatch consecutively -> 1 HBM miss + 3
// L3 hits (r13: y-dim siblings 1024 blocks apart, FETCH 242 MB);
// (2) Pf rotation (r7-proven) restores the ILP the dropped pipeline lost —
// +16 VGPR = 112 unified, still in the 4-wave bucket.
__global__ __launch_bounds__(128,4) void attn2p_kern(const unsigned short* __restrict__ Pm,
    const unsigned short* __restrict__ VA, const float* __restrict__ W2,
    const float* __restrict__ Lpart, unsigned short* __restrict__ Opart){
  const int bxr = blockIdx.x;
  const int go0 = bxr & 3;               // sibling id: output heads go0*2..+1
  const int bx  = bxr >> 2;              // tile id (matches attn1p's bx)
  const int c = bx & 7;                  // chunk
  const int b = (bx>>3) & 1;
  const int it = bx>>4;                  // 0..63
  const int tid = threadIdx.x;
  const int iw = tid>>6, lane = tid&63, m = lane&15, q = lane>>4;
  const int i0 = it*32 + iw*16;
  const int cb = c*(NP/JC2);

  __shared__ unsigned short Osh[32*SPITCH];   // 32 x 128-col slab epilogue

  float w2[8][2];
  #pragma unroll
  for(int h=0;h<8;h++)
    #pragma unroll
    for(int g=0;g<2;g++) w2[h][g]=W2[h*8 + go0*2 + g];

  const unsigned short* VAb = VA + (size_t)b*(8u*4u*(NP/4)*64u);
  const unsigned short* Pw = Pm + (((size_t)bx*2 + iw)*16)*8*64*4;

  // preload jt=0 P fragments (overlaps the rl gather below)
  s16x4 Pf[8];
  #pragma unroll
  for(int g=0;g<8;g++)
    Pf[g] = __builtin_nontemporal_load((const s16x4*)(Pw + ((size_t)g*64 + lane)*4));

  // 1/l for this wave's 16 columns (i = i0 + lane&15); all 8 input heads
  float rl[8];
  #pragma unroll
  for(int g=0;g<8;g++){
    float v = 0.f;
    #pragma unroll
    for(int cc=0;cc<JC1;cc++)
      v += Lpart[(((size_t)cc*NB + b)*NH + g)*NP + i0 + m];
    rl[g] = 1.0f/v;
  }

  f32x4 Oacc[2][4] = {};

  for(int jt=0; jt<NT2; jt++){
    const int j0 = cb + jt*16;
    const size_t jq = (size_t)(j0>>2) + q;
    // unpack current Pf -> s1 (releases Pf registers)
    f32x4 s1[8];
    #pragma unroll
    for(int g=0;g<8;g++){
      u32x2 u = __builtin_bit_cast(u32x2, Pf[g]);
      f32x4 p;
      p[0] = __builtin_bit_cast(float, u.x<<16);
      p[1] = __builtin_bit_cast(float, u.x & 0xffff0000u);
      p[2] = __builtin_bit_cast(float, u.y<<16);
      p[3] = __builtin_bit_cast(float, u.y & 0xffff0000u);
      s1[g] = p * rl[g];
    }
    // rotate: issue next jt's Pf loads; latency hides under mix+pack+MFMA
    if(jt+1 < NT2){
      const unsigned short* Pn = Pw + (size_t)(jt+1)*8*64*4;
      #pragma unroll
      for(int g=0;g<8;g++)
        Pf[g] = __builtin_nontemporal_load((const s16x4*)(Pn + ((size_t)g*64 + lane)*4));
    }
    // per output head: V frags, W2 mix, PV MFMA (Vf live range = one g)
    #pragma unroll
    for(int g=0;g<2;g++){
      const int gh = go0*2 + g;
      s16x4 Vf[4];
      #pragma unroll
      for(int nt=0;nt<4;nt++)
        Vf[nt] = *(const s16x4*)(VAb + ((((size_t)gh*4+nt)*(NP/4) + jq)<<6) + (m<<2));
      f32x4 a = s1[0]*w2[0][g];
      #pragma unroll
      for(int h=1;h<8;h++) a += s1[h]*w2[h][g];
      s16x4 A2 = pack4(a);
      #pragma unroll
      for(int nt=0;nt<4;nt++)
        Oacc[g][nt] = mfma16k16(Vf[nt], A2, Oacc[g][nt]);
    }
  }

  // epilogue: 32x128 slab via LDS, coalesced nontemporal stores
  #pragma unroll
  for(int g=0;g<2;g++)
    #pragma unroll
    for(int nt=0;nt<4;nt++){
      s16x4 pk = pack4(Oacc[g][nt]);
      *(s16x4*)(&Osh[(size_t)(iw*16 + m)*SPITCH + g*64 + nt*16 + 4*q]) = pk;
    }
  __syncthreads();
  unsigned short* Oc = Opart + (size_t)c*NROWS*DM;
  const size_t R0 = (size_t)b*NP + (size_t)it*32;
  const int col0 = go0*128;
  #pragma unroll
  for(int t=0;t<4;t++){
    int idx = t*128 + tid;
    int row = idx>>4, c8 = idx&15;
    u32x4 v = *(const u32x4*)(&Osh[(size_t)row*SPITCH + c8*8]);
    __builtin_nontemporal_store(v, (u32x4*)(Oc + (R0 + row)*DM + col0 + c8*8));
  }
}

// ---------------- chunk reduction: Of = sum_c Opart_c (bf16, f32 accum) ----
__global__ __launch_bounds__(256) void reduce_kern(const unsigned short* __restrict__ Op,
    unsigned short* __restrict__ Of){
  const size_t i = ((size_t)blockIdx.x*256 + threadIdx.x)*8;
  float acc[8] = {};
  #pragma unroll
  for(int cc=0;cc<JC2;cc++){
    u32x4 v = *(const u32x4*)(Op + (size_t)cc*NROWS*DM + i);
    #pragma unroll
    for(int e=0;e<4;e++){
      unsigned u = v[e];
      acc[2*e]   += __builtin_bit_cast(float, u<<16);
      acc[2*e+1] += __builtin_bit_cast(float, u & 0xffff0000u);
    }
  }
  u32x4 o;
  #pragma unroll
  for(int e=0;e<4;e++)
    o[e] = (unsigned)f2bf(acc[2*e]) | ((unsigned)f2bf(acc[2*e+1])<<16);
  *(u32x4*)(Of + i) = o;
}

// ---------------- output projection: out = Of @ Wproj (single pass) -------
__global__ __launch_bounds__(256) void oproj_kern(const unsigned short* __restrict__ Of,
    const unsigned short* __restrict__ WT, float* __restrict__ out){
  const int nb = blockIdx.y;
  const int R0 = blockIdx.x*64;
  const int tid = threadIdx.x;
  const int w = tid>>6, lane = tid&63, m = lane&15, q = lane>>4;
  const unsigned short* Wp = WT + (size_t)3*DM*DM;
  f32x4 acc[4] = {};
  const unsigned short* brow = Wp + (size_t)(nb*64 + m)*DM + q*8;
  const unsigned short* arow = Of + (size_t)(R0 + w*16 + m)*DM + q*8;
  for(int k=0;k<DM;k+=32){
    s16x8 A = *(const s16x8*)(arow + k);
    #pragma unroll
    for(int nt=0;nt<4;nt++){
      s16x8 B = *(const s16x8*)(brow + (size_t)nt*16*DM + k);
      acc[nt] = mfma16(A, B, acc[nt]);
    }
  }
  #pragma unroll
  for(int nt=0;nt<4;nt++)
    #pragma unroll
    for(int r=0;r<4;r++)
      out[(size_t)(R0 + w*16 + q*4 + r)*DM + nb*64 + nt*16 + m] = acc[nt][r];
}

extern "C" void kernel_launch(void* const* d_in, const int* in_sizes, int n_in,
                              void* d_out, int out_size, void* d_ws, size_t ws_size,
                              hipStream_t stream){
  (void)in_sizes; (void)n_in; (void)out_size;
  const float* x  = (const float*)d_in[0];
  const float* Wq = (const float*)d_in[1];
  const float* Wk = (const float*)d_in[2];
  const float* Wv = (const float*)d_in[3];
  const float* W1 = (const float*)d_in[4];
  const float* W2 = (const float*)d_in[5];
  const float* Wp = (const float*)d_in[6];

  char* ws = (char*)d_ws;
  unsigned short* xb = (unsigned short*)ws;  ws += (size_t)NROWS*DM*2;     // 4 MB
  unsigned short* WT = (unsigned short*)ws;  ws += (size_t)4*DM*DM*2;      // 2 MB
  unsigned short* Qs = (unsigned short*)ws;  ws += (size_t)NB*NH*NP*DH*2;  // 4 MB
  unsigned short* Kk = (unsigned short*)ws;  ws += (size_t)NB*NH*NP*DH*2;  // 4 MB
  unsigned short* VA = (unsigned short*)ws;  ws += (size_t)NB*NH*DH*NP*2;  // 4 MB
  float*          Lp = (float*)ws;           ws += (size_t)JC1*NB*NH*NP*4; // 2 MB
  unsigned short* Op = (unsigned short*)ws;  ws += (size_t)JC2*NROWS*DM*2; // 32 MB
  unsigned short* Pm = (unsigned short*)ws;  // 128 MiB if it fits
  const size_t pm_bytes = (size_t)1024*2*16*8*64*4*2;  // [bx][iw][jt][g][lane]x4
  const size_t need = (size_t)((char*)Pm - (char*)d_ws) + pm_bytes;
  unsigned short* Of = xb;  // alias: xb is dead after qkv_kern

  prep_x<<<NROWS*DM/1024, 256, 0, stream>>>(x, xb);
  prep_w<<<dim3(8,8,4), 256, 0, stream>>>(Wq, Wk, Wv, Wp, WT);
  qkv_kern<<<dim3(64,8,3), 256, 0, stream>>>(xb, WT, Qs, Kk, VA);
  if(ws_size >= need){
    attn1p_kern<<<dim3(1024), 128, 0, stream>>>(Qs, Kk, W1, Lp, Pm);
    attn2p_kern<<<dim3(4096), 128, 0, stream>>>(Pm, VA, W2, Lp, Op);
  } else {
    attn1_kern<<<dim3(1024), 128, 0, stream>>>(Qs, Kk, W1, Lp);
    attn2_kern<<<dim3(1024), 128, 0, stream>>>(Qs, Kk, VA, W1, W2, Lp, Op);
  }
  reduce_kern<<<dim3(NROWS*DM/2048), 256, 0, stream>>>(Op, Of);
  oproj_kern<<<dim3(64,8), 256, 0, stream>>>(Of, WT, (float*)d_out);
}

// Round 16
// 310.925 us; speedup vs baseline: 1.1275x; 1.1275x over previous
//
#include <hip/hip_runtime.h>
#include <hip/hip_bf16.h>

#define DM 512
#define DH 64
#define NH 8
#define NP 2048
#define NB 2
#define NROWS (NB*NP)
#define JC1 8            // attn1 j-chunks (chunk = 256 j, 16 jt of 16)
#define JC2 8            // attn2 j-chunks (chunk = 256 j, 16 jt of 16)
#define NT1 (NP/JC1/16)  // 16
#define NT2 (NP/JC2/16)  // 16
#define OPITCH 520       // LDS pitch (shorts) for 512-wide tiles
#define SPITCH 264       // LDS pitch (shorts) for 256-wide slab (attn2p epilogue)

typedef short s16x8 __attribute__((ext_vector_type(8)));
typedef short s16x4 __attribute__((ext_vector_type(4)));
typedef float f32x4 __attribute__((ext_vector_type(4)));
typedef unsigned int u32x4 __attribute__((ext_vector_type(4)));
typedef unsigned int u32x2 __attribute__((ext_vector_type(2)));

__device__ __forceinline__ unsigned short f2bf(float f){
  __hip_bfloat16 h = __float2bfloat16(f);
  return __builtin_bit_cast(unsigned short, h);
}

__device__ __forceinline__ f32x4 mfma16(s16x8 a, s16x8 b, f32x4 c){
  return __builtin_amdgcn_mfma_f32_16x16x32_bf16(a, b, c, 0, 0, 0);
}

__device__ __forceinline__ f32x4 mfma16k16(s16x4 a, s16x4 b, f32x4 c){
#if __has_builtin(__builtin_amdgcn_mfma_f32_16x16x16bf16_1k)
  return __builtin_amdgcn_mfma_f32_16x16x16bf16_1k(a, b, c, 0, 0, 0);
#else
  asm volatile("v_mfma_f32_16x16x16_bf16 %0, %1, %2, %0\n\ts_nop 7\n\ts_nop 7"
               : "+v"(c) : "v"(a), "v"(b));
  return c;
#endif
}

__device__ __forceinline__ s16x4 pack4(f32x4 a){
  u32x2 u;
  u.x = (unsigned)f2bf(a[0]) | ((unsigned)f2bf(a[1])<<16);
  u.y = (unsigned)f2bf(a[2]) | ((unsigned)f2bf(a[3])<<16);
  return __builtin_bit_cast(s16x4, u);
}

// ---------------- prep: x fp32 -> bf16 ----------------
__global__ void prep_x(const float* __restrict__ x, unsigned short* __restrict__ xb){
  int i = (blockIdx.x*256 + threadIdx.x)*4;
  float4 v = *(const float4*)(x + i);
  unsigned short s0=f2bf(v.x), s1=f2bf(v.y), s2=f2bf(v.z), s3=f2bf(v.w);
  uint2 u; u.x = (unsigned)s0 | ((unsigned)s1<<16); u.y = (unsigned)s2 | ((unsigned)s3<<16);
  *(uint2*)(xb + i) = u;
}

// ---------------- prep: transpose weights to [n][k] bf16 ----------------
__global__ void prep_w(const float* __restrict__ Wq, const float* __restrict__ Wk,
                       const float* __restrict__ Wv, const float* __restrict__ Wp,
                       unsigned short* __restrict__ WT){
  __shared__ float t[64][65];
  const float* W = (blockIdx.z==0)?Wq:(blockIdx.z==1)?Wk:(blockIdx.z==2)?Wv:Wp;
  const int k0 = blockIdx.x*64, n0 = blockIdx.y*64;
  const int c = threadIdx.x&63, rq = threadIdx.x>>6;
  #pragma unroll
  for(int rr=0;rr<16;rr++){
    int kl = rq*16+rr;
    t[kl][c] = W[(size_t)(k0+kl)*DM + n0 + c];
  }
  __syncthreads();
  unsigned short* o = WT + (size_t)blockIdx.z*DM*DM;
  #pragma unroll
  for(int rr=0;rr<16;rr++){
    int nl = rq*16+rr;
    o[(size_t)(n0+nl)*DM + k0 + c] = f2bf(t[c][nl]);
  }
}

// ---------------- QKV projection GEMM ----------------
// z=0: Qs (scaled 1/8) [b][h][p][d]; z=1: K [b][h][p][d];
// z=2: VA — V^T in K16-A-frag-native layout [b][g][nt][p/4][d&15][p&3]
__global__ __launch_bounds__(256) void qkv_kern(const unsigned short* __restrict__ xb,
    const unsigned short* __restrict__ WT,
    unsigned short* __restrict__ Qs, unsigned short* __restrict__ Kk,
    unsigned short* __restrict__ VA){
  const int z = blockIdx.z, h = blockIdx.y;
  const int R0 = blockIdx.x*64;
  const int tid = threadIdx.x;
  const int w = tid>>6, lane = tid&63, m = lane&15, q = lane>>4;
  const unsigned short* Wz = WT + (size_t)z*DM*DM;
  f32x4 acc[4] = {};
  const unsigned short* arow = xb + (size_t)(R0 + w*16 + m)*DM + q*8;
  const unsigned short* brow = Wz + (size_t)(h*64 + m)*DM + q*8;
  for(int k=0;k<DM;k+=32){
    s16x8 A = *(const s16x8*)(arow + k);
    #pragma unroll
    for(int nt=0;nt<4;nt++){
      s16x8 B = *(const s16x8*)(brow + (size_t)nt*16*DM + k);
      acc[nt] = mfma16(A, B, acc[nt]);
    }
  }
  __shared__ float t[64][65];
  const float scale = (z==0) ? 0.125f : 1.0f;
  #pragma unroll
  for(int nt=0;nt<4;nt++)
    #pragma unroll
    for(int r=0;r<4;r++)
      t[w*16 + q*4 + r][nt*16 + m] = acc[nt][r]*scale;
  __syncthreads();
  const int b = R0>>11, p0 = R0&2047;
  if(z<2){
    unsigned short* outp = (z==0)? Qs : Kk;
    int pl = tid>>2, c0 = (tid&3)*16;
    unsigned short vbuf[16];
    #pragma unroll
    for(int i=0;i<16;i++) vbuf[i]=f2bf(t[pl][c0+i]);
    unsigned short* dst = outp + ((size_t)(b*NH+h)*NP + p0+pl)*DH + c0;
    uint4 u0, u1;
    u0.x=(unsigned)vbuf[0]|((unsigned)vbuf[1]<<16);  u0.y=(unsigned)vbuf[2]|((unsigned)vbuf[3]<<16);
    u0.z=(unsigned)vbuf[4]|((unsigned)vbuf[5]<<16);  u0.w=(unsigned)vbuf[6]|((unsigned)vbuf[7]<<16);
    u1.x=(unsigned)vbuf[8]|((unsigned)vbuf[9]<<16);  u1.y=(unsigned)vbuf[10]|((unsigned)vbuf[11]<<16);
    u1.z=(unsigned)vbuf[12]|((unsigned)vbuf[13]<<16);u1.w=(unsigned)vbuf[14]|((unsigned)vbuf[15]<<16);
    *(uint4*)dst = u0; *(uint4*)(dst+8) = u1;
  } else {
    int d = tid>>2, c0 = (tid&3)*16;
    unsigned short* vb = VA + (size_t)b*(8u*4u*(NP/4)*64u)
        + ((size_t)(h*4 + (d>>4))*(NP/4))*64 + (size_t)(d&15)*4;
    #pragma unroll
    for(int grp=0; grp<4; grp++){
      int pl = c0 + grp*4;
      unsigned short v4[4];
      #pragma unroll
      for(int tt=0; tt<4; tt++) v4[tt] = f2bf(t[pl+tt][d]);
      uint2 u; u.x = (unsigned)v4[0] | ((unsigned)v4[1]<<16);
      u.y = (unsigned)v4[2] | ((unsigned)v4[3]<<16);
      *(uint2*)(vb + (size_t)((p0 + pl)>>2)*64) = u;
    }
  }
}

// ---------------- attn sweep 1 (fallback): denominators only --------------
// DO NOT peephole the attn inner loops: r1/r2 showed any perturbation of the
// instruction stream tips the 256-reg knife edge into scratch spills.
// NOTE (r11): fusing the two sweeps is mathematically INVALID — the W2 mix
// couples P-head h with V-head go; two sweeps (or P materialization) forced.
__global__ __launch_bounds__(128,2) void attn1_kern(const unsigned short* __restrict__ Qs,
    const unsigned short* __restrict__ Kk, const float* __restrict__ W1,
    float* __restrict__ Lpart){
  const int bx = blockIdx.x;
  const int c = bx & 7;
  const int b = (bx>>3) & 1;
  const int it = bx>>4;                  // 0..63
  const int tid = threadIdx.x;
  const int iw = tid>>6, lane = tid&63, m = lane&15, q = lane>>4;
  const int i0 = it*32 + iw*16;
  const int cb = c*(NP/JC1);

  float w1[8][8];
  #pragma unroll
  for(int h=0;h<8;h++)
    #pragma unroll
    for(int g=0;g<8;g++) w1[h][g]=W1[h*8+g];

  const unsigned short* Qb = Qs + (size_t)b*NH*NP*DH;
  const unsigned short* Kb = Kk + (size_t)b*NH*NP*DH;

  s16x8 Qf[8][2];
  #pragma unroll
  for(int h=0;h<8;h++){
    const unsigned short* qp = Qb + ((size_t)h*NP + i0 + m)*DH + q*8;
    Qf[h][0] = *(const s16x8*)(qp);
    Qf[h][1] = *(const s16x8*)(qp + 32);
  }

  float lacc[8] = {};
  for(int jt=0; jt<NT1; jt++){
    const int j0 = cb + jt*16;
    s16x8 K[8][2];
    #pragma unroll
    for(int h=0;h<8;h++){
      const unsigned short* kp = Kb + ((size_t)h*NP + j0 + m)*DH + q*8;
      K[h][0] = *(const s16x8*)(kp);
      K[h][1] = *(const s16x8*)(kp + 32);
    }
    f32x4 s1[8] = {};
    #pragma unroll
    for(int h=0;h<8;h++){
      f32x4 z = {};
      z = mfma16(K[h][0], Qf[h][0], z);       // A=K (m=j), B=Q (n=i) -> S^T
      f32x4 Sh = mfma16(K[h][1], Qf[h][1], z);
      #pragma unroll
      for(int g=0;g<8;g++) s1[g] += Sh*w1[h][g];
    }
    #pragma unroll
    for(int g=0;g<8;g++)
      #pragma unroll
      for(int r=0;r<4;r++) lacc[g] += __expf(s1[g][r]);
  }
  #pragma unroll
  for(int g=0;g<8;g++){
    float v = lacc[g];
    v += __shfl_xor(v,16); v += __shfl_xor(v,32);
    lacc[g] = v;
  }
  if(lane < 16){
    #pragma unroll
    for(int g=0;g<8;g++)
      Lpart[(((size_t)c*NB + b)*NH + g)*NP + i0 + lane] = lacc[g];
  }
}

// ---------------- attn sweep 1 (P-store, per-h K-rotated) -----------------
// r10 verified best: full 8 heads, grid 1024, live-set-neutral K rotation —
// K[h] reloaded in place with jt+1's tile immediately after its two MFMAs
// consume it. Each K load gets ~7/8 of the h-loop + exp/pack tail of cover.
__global__ __launch_bounds__(128,2) void attn1p_kern(const unsigned short* __restrict__ Qs,
    const unsigned short* __restrict__ Kk, const float* __restrict__ W1,
    float* __restrict__ Lpart, unsigned short* __restrict__ Pm){
  const int bx = blockIdx.x;
  const int c = bx & 7;
  const int b = (bx>>3) & 1;
  const int it = bx>>4;                  // 0..63
  const int tid = threadIdx.x;
  const int iw = tid>>6, lane = tid&63, m = lane&15, q = lane>>4;
  const int i0 = it*32 + iw*16;
  const int cb = c*(NP/JC1);

  float w1[8][8];
  #pragma unroll
  for(int h=0;h<8;h++)
    #pragma unroll
    for(int g=0;g<8;g++) w1[h][g]=W1[h*8+g];

  const unsigned short* Qb = Qs + (size_t)b*NH*NP*DH;
  const unsigned short* Kb = Kk + (size_t)b*NH*NP*DH;
  unsigned short* Pw = Pm + (((size_t)bx*2 + iw)*16)*8*64*4;

  s16x8 Qf[8][2];
  #pragma unroll
  for(int h=0;h<8;h++){
    const unsigned short* qp = Qb + ((size_t)h*NP + i0 + m)*DH + q*8;
    Qf[h][0] = *(const s16x8*)(qp);
    Qf[h][1] = *(const s16x8*)(qp + 32);
  }

  // preload K tile for jt=0
  s16x8 K[8][2];
  #pragma unroll
  for(int h=0;h<8;h++){
    const unsigned short* kp = Kb + ((size_t)h*NP + cb + m)*DH + q*8;
    K[h][0] = *(const s16x8*)(kp);
    K[h][1] = *(const s16x8*)(kp + 32);
  }

  float lacc[8] = {};
  for(int jt=0; jt<NT1; jt++){
    const int j1 = cb + (jt+1)*16;
    f32x4 s1[8] = {};
    #pragma unroll
    for(int h=0;h<8;h++){
      f32x4 z = {};
      z = mfma16(K[h][0], Qf[h][0], z);       // A=K (m=j), B=Q (n=i) -> S^T
      f32x4 Sh = mfma16(K[h][1], Qf[h][1], z);
      // K[h] dead now: reload in place with next jt's tile
      if(jt+1 < NT1){
        const unsigned short* kp = Kb + ((size_t)h*NP + j1 + m)*DH + q*8;
        K[h][0] = *(const s16x8*)(kp);
        K[h][1] = *(const s16x8*)(kp + 32);
      }
      #pragma unroll
      for(int g=0;g<8;g++) s1[g] += Sh*w1[h][g];
    }
    unsigned short* Pjt = Pw + (size_t)jt*8*64*4;
    #pragma unroll
    for(int g=0;g<8;g++){
      f32x4 e;
      #pragma unroll
      for(int r=0;r<4;r++){ e[r] = __expf(s1[g][r]); lacc[g] += e[r]; }
      s16x4 pk = pack4(e);
      __builtin_nontemporal_store(pk, (s16x4*)(Pjt + ((size_t)g*64 + lane)*4));
    }
  }
  #pragma unroll
  for(int g=0;g<8;g++){
    float v = lacc[g];
    v += __shfl_xor(v,16); v += __shfl_xor(v,32);
    lacc[g] = v;
  }
  if(lane < 16){
    #pragma unroll
    for(int g=0;g<8;g++)
      Lpart[(((size_t)c*NB + b)*NH + g)*NP + i0 + lane] = lacc[g];
  }
}

// ---------------- attn sweep 2 (fallback): full recompute -----------------
__global__ __launch_bounds__(128,2) void attn2_kern(const unsigned short* __restrict__ Qs,
    const unsigned short* __restrict__ Kk, const unsigned short* __restrict__ VA,
    const float* __restrict__ W1, const float* __restrict__ W2,
    const float* __restrict__ Lpart, unsigned short* __restrict__ Opart){
  const int bx = blockIdx.x;
  const int c = bx & 7;
  const int b = (bx>>3) & 1;
  const int it = bx>>4;
  const int tid = threadIdx.x;
  const int iw = tid>>6, lane = tid&63, m = lane&15, q = lane>>4;
  const int i0 = it*32 + iw*16;
  const int cb = c*(NP/JC2);

  __shared__ unsigned short Osh[32*OPITCH];

  float w1[8][8], w2[8][8];
  #pragma unroll
  for(int h=0;h<8;h++)
    #pragma unroll
    for(int g=0;g<8;g++){ w1[h][g]=W1[h*8+g]; w2[h][g]=W2[h*8+g]; }

  const unsigned short* Qb = Qs + (size_t)b*NH*NP*DH;
  const unsigned short* Kb = Kk + (size_t)b*NH*NP*DH;
  const unsigned short* VAb = VA + (size_t)b*(8u*4u*(NP/4)*64u);

  {
    const int qr = lane>>2, qc = (lane&3)*16;
    #pragma unroll
    for(int h=0;h<8;h++){
      const unsigned short* src = Qb + ((size_t)h*NP + i0 + qr)*DH + qc;
      unsigned short* dst = &Osh[(size_t)(iw*16+qr)*OPITCH + h*64 + qc];
      *(u32x4*)dst = *(const u32x4*)src;
      *(u32x4*)(dst+8) = *(const u32x4*)(src+8);
    }
  }

  float rl[8];
  #pragma unroll
  for(int g=0;g<8;g++){
    float v = 0.f;
    #pragma unroll
    for(int cc=0;cc<JC1;cc++)
      v += Lpart[(((size_t)cc*NB + b)*NH + g)*NP + i0 + m];
    rl[g] = 1.0f/v;
  }

  f32x4 Oacc[8][4] = {};
  const unsigned short* QL = &Osh[(size_t)(iw*16+m)*OPITCH];

  for(int jt=0; jt<NT2; jt++){
    const int j0 = cb + jt*16;
    s16x8 K[8][2];
    #pragma unroll
    for(int h=0;h<8;h++){
      const unsigned short* kp = Kb + ((size_t)h*NP + j0 + m)*DH + q*8;
      K[h][0] = *(const s16x8*)(kp);
      K[h][1] = *(const s16x8*)(kp + 32);
    }
    f32x4 s1[8] = {};
    #pragma unroll
    for(int h=0;h<8;h++){
      s16x8 q0 = *(const s16x8*)(QL + h*64 + q*8);
      s16x8 q1 = *(const s16x8*)(QL + h*64 + 32 + q*8);
      f32x4 z = {};
      z = mfma16(K[h][0], q0, z);
      f32x4 Sh = mfma16(K[h][1], q1, z);
      #pragma unroll
      for(int g=0;g<8;g++) s1[g] += Sh*w1[h][g];
    }
    s16x4 Vf[8][4];
    const size_t jq = (size_t)(j0>>2) + q;
    #pragma unroll
    for(int g=0;g<8;g++)
      #pragma unroll
      for(int nt=0;nt<4;nt++)
        Vf[g][nt] = *(const s16x4*)(VAb + ((((size_t)g*4+nt)*(NP/4) + jq)<<6) + (m<<2));
    #pragma unroll
    for(int g=0;g<8;g++){
      #pragma unroll
      for(int r=0;r<4;r++) s1[g][r] = __expf(s1[g][r]);
      s1[g] *= rl[g];
    }
    s16x4 A2[8];
    #pragma unroll
    for(int go=0;go<8;go++){
      f32x4 a = s1[0]*w2[0][go];
      #pragma unroll
      for(int h=1;h<8;h++) a += s1[h]*w2[h][go];
      A2[go] = pack4(a);
    }
    #pragma unroll
    for(int g=0;g<8;g++)
      #pragma unroll
      for(int nt=0;nt<4;nt++)
        Oacc[g][nt] = mfma16k16(Vf[g][nt], A2[g], Oacc[g][nt]);
  }

  #pragma unroll
  for(int g=0;g<8;g++)
    #pragma unroll
    for(int nt=0;nt<4;nt++){
      s16x4 pk = pack4(Oacc[g][nt]);
      *(s16x4*)(&Osh[(size_t)(iw*16 + m)*OPITCH + g*64 + nt*16 + 4*q]) = pk;
    }
  __syncthreads();
  unsigned short* Oc = Opart + (size_t)c*NROWS*DM;
  const size_t R0 = (size_t)b*NP + (size_t)it*32;
  #pragma unroll
  for(int t=0;t<16;t++){
    int idx = t*128 + tid;
    int row = idx>>6, c8 = idx&63;
    u32x4 v = *(const u32x4*)(&Osh[(size_t)row*OPITCH + c8*8]);
    __builtin_nontemporal_store(v, (u32x4*)(Oc + (R0 + row)*DM + c8*8));
  }
}

// ---------------- attn sweep 2 (P-load, go-split, deep-rotated) -----------
// r12 verified config (2-step Pf+Vf pipeline, go-half, VGPR 120). One change
// vs r12: Pm loads are PLAIN (no nontemporal hint) — Pm is read twice
// (go0=0,1), and the nt hint marked lines for early eviction, working
// against the L3 reuse of the second pass. Hint-only change, zero codegen
// footprint. (r13/r14 measured: go-quarter variants lose — every extra Pm
// pass costs more HBM time than added occupancy recovers.)
__global__ __launch_bounds__(128,2) void attn2p_kern(const unsigned short* __restrict__ Pm,
    const unsigned short* __restrict__ VA, const float* __restrict__ W2,
    const float* __restrict__ Lpart, unsigned short* __restrict__ Opart){
  const int bx = blockIdx.x;
  const int go0 = blockIdx.y;            // 0/1 -> output heads go0*4..go0*4+3
  const int c = bx & 7;                  // chunk, pinned to XCD
  const int b = (bx>>3) & 1;
  const int it = bx>>4;                  // 0..63
  const int tid = threadIdx.x;
  const int iw = tid>>6, lane = tid&63, m = lane&15, q = lane>>4;
  const int i0 = it*32 + iw*16;
  const int cb = c*(NP/JC2);

  __shared__ unsigned short Osh[32*SPITCH];   // 32 x 256-col slab epilogue

  float w2[8][4];
  #pragma unroll
  for(int h=0;h<8;h++)
    #pragma unroll
    for(int g=0;g<4;g++) w2[h][g]=W2[h*8 + go0*4 + g];

  const unsigned short* VAb = VA + (size_t)b*(8u*4u*(NP/4)*64u);
  const unsigned short* Pw = Pm + (((size_t)bx*2 + iw)*16)*8*64*4;

  s16x4 PfA[8], PfB[8], VfA[4][4], VfB[4][4];

  // prologue: load jt=0 fragments (overlaps the rl gather below)
  #pragma unroll
  for(int g=0;g<8;g++)
    PfA[g] = *(const s16x4*)(Pw + ((size_t)g*64 + lane)*4);
  {
    const size_t jq0 = (size_t)(cb>>2) + q;
    #pragma unroll
    for(int g=0;g<4;g++){
      const int gh = go0*4 + g;
      #pragma unroll
      for(int nt=0;nt<4;nt++)
        VfA[g][nt] = *(const s16x4*)(VAb + ((((size_t)gh*4+nt)*(NP/4) + jq0)<<6) + (m<<2));
    }
  }

  // 1/l for this wave's 16 columns (i = i0 + lane&15); all 8 input heads
  float rl[8];
  #pragma unroll
  for(int g=0;g<8;g++){
    float v = 0.f;
    #pragma unroll
    for(int cc=0;cc<JC1;cc++)
      v += Lpart[(((size_t)cc*NB + b)*NH + g)*NP + i0 + m];
    rl[g] = 1.0f/v;
  }

  f32x4 Oacc[4][4] = {};

  for(int jt2=0; jt2<NT2; jt2+=2){
    // ---- even step: consume A (jt2), prefetch B (jt2+1, always valid) ----
    {
      f32x4 s1[8];
      #pragma unroll
      for(int g=0;g<8;g++){
        u32x2 u = __builtin_bit_cast(u32x2, PfA[g]);
        f32x4 p;
        p[0] = __builtin_bit_cast(float, u.x<<16);
        p[1] = __builtin_bit_cast(float, u.x & 0xffff0000u);
        p[2] = __builtin_bit_cast(float, u.y<<16);
        p[3] = __builtin_bit_cast(float, u.y & 0xffff0000u);
        s1[g] = p * rl[g];
      }
      const unsigned short* Pn = Pw + (size_t)(jt2+1)*8*64*4;
      #pragma unroll
      for(int g=0;g<8;g++)
        PfB[g] = *(const s16x4*)(Pn + ((size_t)g*64 + lane)*4);
      const size_t jqn = (size_t)((cb + (jt2+1)*16)>>2) + q;
      #pragma unroll
      for(int g=0;g<4;g++){
        const int gh = go0*4 + g;
        #pragma unroll
        for(int nt=0;nt<4;nt++)
          VfB[g][nt] = *(const s16x4*)(VAb + ((((size_t)gh*4+nt)*(NP/4) + jqn)<<6) + (m<<2));
      }
      #pragma unroll
      for(int g=0;g<4;g++){
        f32x4 a = s1[0]*w2[0][g];
        #pragma unroll
        for(int h=1;h<8;h++) a += s1[h]*w2[h][g];
        s16x4 A2 = pack4(a);
        #pragma unroll
        for(int nt=0;nt<4;nt++)
          Oacc[g][nt] = mfma16k16(VfA[g][nt], A2, Oacc[g][nt]);
      }
    }
    // ---- odd step: consume B (jt2+1), prefetch A (jt2+2 if valid) ----
    {
      f32x4 s1[8];
      #pragma unroll
      for(int g=0;g<8;g++){
        u32x2 u = __builtin_bit_cast(u32x2, PfB[g]);
        f32x4 p;
        p[0] = __builtin_bit_cast(float, u.x<<16);
        p[1] = __builtin_bit_cast(float, u.x & 0xffff0000u);
        p[2] = __builtin_bit_cast(float, u.y<<16);
        p[3] = __builtin_bit_cast(float, u.y & 0xffff0000u);
        s1[g] = p * rl[g];
      }
      if(jt2+2 < NT2){
        const unsigned short* Pn = Pw + (size_t)(jt2+2)*8*64*4;
        #pragma unroll
        for(int g=0;g<8;g++)
          PfA[g] = *(const s16x4*)(Pn + ((size_t)g*64 + lane)*4);
        const size_t jqn = (size_t)((cb + (jt2+2)*16)>>2) + q;
        #pragma unroll
        for(int g=0;g<4;g++){
          const int gh = go0*4 + g;
          #pragma unroll
          for(int nt=0;nt<4;nt++)
            VfA[g][nt] = *(const s16x4*)(VAb + ((((size_t)gh*4+nt)*(NP/4) + jqn)<<6) + (m<<2));
        }
      }
      #pragma unroll
      for(int g=0;g<4;g++){
        f32x4 a = s1[0]*w2[0][g];
        #pragma unroll
        for(int h=1;h<8;h++) a += s1[h]*w2[h][g];
        s16x4 A2 = pack4(a);
        #pragma unroll
        for(int nt=0;nt<4;nt++)
          Oacc[g][nt] = mfma16k16(VfB[g][nt], A2, Oacc[g][nt]);
      }
    }
  }

  // epilogue: 32x256 slab via LDS, coalesced nontemporal stores
  #pragma unroll
  for(int g=0;g<4;g++)
    #pragma unroll
    for(int nt=0;nt<4;nt++){
      s16x4 pk = pack4(Oacc[g][nt]);
      *(s16x4*)(&Osh[(size_t)(iw*16 + m)*SPITCH + g*64 + nt*16 + 4*q]) = pk;
    }
  __syncthreads();
  unsigned short* Oc = Opart + (size_t)c*NROWS*DM;
  const size_t R0 = (size_t)b*NP + (size_t)it*32;
  const int col0 = go0*256;
  #pragma unroll
  for(int t=0;t<8;t++){
    int idx = t*128 + tid;
    int row = idx>>5, c8 = idx&31;
    u32x4 v = *(const u32x4*)(&Osh[(size_t)row*SPITCH + c8*8]);
    __builtin_nontemporal_store(v, (u32x4*)(Oc + (R0 + row)*DM + col0 + c8*8));
  }
}

// ---------------- chunk reduction: Of = sum_c Opart_c (bf16, f32 accum) ----
__global__ __launch_bounds__(256) void reduce_kern(const unsigned short* __restrict__ Op,
    unsigned short* __restrict__ Of){
  const size_t i = ((size_t)blockIdx.x*256 + threadIdx.x)*8;
  float acc[8] = {};
  #pragma unroll
  for(int cc=0;cc<JC2;cc++){
    u32x4 v = *(const u32x4*)(Op + (size_t)cc*NROWS*DM + i);
    #pragma unroll
    for(int e=0;e<4;e++){
      unsigned u = v[e];
      acc[2*e]   += __builtin_bit_cast(float, u<<16);
      acc[2*e+1] += __builtin_bit_cast(float, u & 0xffff0000u);
    }
  }
  u32x4 o;
  #pragma unroll
  for(int e=0;e<4;e++)
    o[e] = (unsigned)f2bf(acc[2*e]) | ((unsigned)f2bf(acc[2*e+1])<<16);
  *(u32x4*)(Of + i) = o;
}

// ---------------- output projection: out = Of @ Wproj (single pass) -------
__global__ __launch_bounds__(256) void oproj_kern(const unsigned short* __restrict__ Of,
    const unsigned short* __restrict__ WT, float* __restrict__ out){
  const int nb = blockIdx.y;
  const int R0 = blockIdx.x*64;
  const int tid = threadIdx.x;
  const int w = tid>>6, lane = tid&63, m = lane&15, q = lane>>4;
  const unsigned short* Wp = WT + (size_t)3*DM*DM;
  f32x4 acc[4] = {};
  const unsigned short* brow = Wp + (size_t)(nb*64 + m)*DM + q*8;
  const unsigned short* arow = Of + (size_t)(R0 + w*16 + m)*DM + q*8;
  for(int k=0;k<DM;k+=32){
    s16x8 A = *(const s16x8*)(arow + k);
    #pragma unroll
    for(int nt=0;nt<4;nt++){
      s16x8 B = *(const s16x8*)(brow + (size_t)nt*16*DM + k);
      acc[nt] = mfma16(A, B, acc[nt]);
    }
  }
  #pragma unroll
  for(int nt=0;nt<4;nt++)
    #pragma unroll
    for(int r=0;r<4;r++)
      out[(size_t)(R0 + w*16 + q*4 + r)*DM + nb*64 + nt*16 + m] = acc[nt][r];
}

extern "C" void kernel_launch(void* const* d_in, const int* in_sizes, int n_in,
                              void* d_out, int out_size, void* d_ws, size_t ws_size,
                              hipStream_t stream){
  (void)in_sizes; (void)n_in; (void)out_size;
  const float* x  = (const float*)d_in[0];
  const float* Wq = (const float*)d_in[1];
  const float* Wk = (const float*)d_in[2];
  const float* Wv = (const float*)d_in[3];
  const float* W1 = (const float*)d_in[4];
  const float* W2 = (const float*)d_in[5];
  const float* Wp = (const float*)d_in[6];

  char* ws = (char*)d_ws;
  unsigned short* xb = (unsigned short*)ws;  ws += (size_t)NROWS*DM*2;     // 4 MB
  unsigned short* WT = (unsigned short*)ws;  ws += (size_t)4*DM*DM*2;      // 2 MB
  unsigned short* Qs = (unsigned short*)ws;  ws += (size_t)NB*NH*NP*DH*2;  // 4 MB
  unsigned short* Kk = (unsigned short*)ws;  ws += (size_t)NB*NH*NP*DH*2;  // 4 MB
  unsigned short* VA = (unsigned short*)ws;  ws += (size_t)NB*NH*DH*NP*2;  // 4 MB
  float*          Lp = (float*)ws;           ws += (size_t)JC1*NB*NH*NP*4; // 2 MB
  unsigned short* Op = (unsigned short*)ws;  ws += (size_t)JC2*NROWS*DM*2; // 32 MB
  unsigned short* Pm = (unsigned short*)ws;  // 128 MiB if it fits
  const size_t pm_bytes = (size_t)1024*2*16*8*64*4*2;  // [bx][iw][jt][g][lane]x4
  const size_t need = (size_t)((char*)Pm - (char*)d_ws) + pm_bytes;
  unsigned short* Of = xb;  // alias: xb is dead after qkv_kern

  prep_x<<<NROWS*DM/1024, 256, 0, stream>>>(x, xb);
  prep_w<<<dim3(8,8,4), 256, 0, stream>>>(Wq, Wk, Wv, Wp, WT);
  qkv_kern<<<dim3(64,8,3), 256, 0, stream>>>(xb, WT, Qs, Kk, VA);
  if(ws_size >= need){
    attn1p_kern<<<dim3(1024), 128, 0, stream>>>(Qs, Kk, W1, Lp, Pm);
    attn2p_kern<<<dim3(1024,2), 128, 0, stream>>>(Pm, VA, W2, Lp, Op);
  } else {
    attn1_kern<<<dim3(1024), 128, 0, stream>>>(Qs, Kk, W1, Lp);
    attn2_kern<<<dim3(1024), 128, 0, stream>>>(Qs, Kk, VA, W1, W2, Lp, Op);
  }
  reduce_kern<<<dim3(NROWS*DM/2048), 256, 0, stream>>>(Op, Of);
  oproj_kern<<<dim3(64,8), 256, 0, stream>>>(Of, WT, (float*)d_out);
}

// Round 17
// 302.266 us; speedup vs baseline: 1.1598x; 1.0286x over previous
//
#include <hip/hip_runtime.h>
#include <hip/hip_bf16.h>

#define DM 512
#define DH 64
#define NH 8
#define NP 2048
#define NB 2
#define NROWS (NB*NP)
#define JC1 8            // attn1 j-chunks (chunk = 256 j, 16 jt of 16)
#define JC2 8            // attn2 j-chunks (chunk = 256 j, 16 jt of 16)
#define NT1 (NP/JC1/16)  // 16
#define NT2 (NP/JC2/16)  // 16
#define OPITCH 520       // LDS pitch (shorts) for 512-wide tiles
#define SPITCH 264       // LDS pitch (shorts) for 256-wide slab (attn2p epilogue)

typedef short s16x8 __attribute__((ext_vector_type(8)));
typedef short s16x4 __attribute__((ext_vector_type(4)));
typedef float f32x4 __attribute__((ext_vector_type(4)));
typedef unsigned int u32x4 __attribute__((ext_vector_type(4)));
typedef unsigned int u32x2 __attribute__((ext_vector_type(2)));

__device__ __forceinline__ unsigned short f2bf(float f){
  __hip_bfloat16 h = __float2bfloat16(f);
  return __builtin_bit_cast(unsigned short, h);
}

__device__ __forceinline__ f32x4 mfma16(s16x8 a, s16x8 b, f32x4 c){
  return __builtin_amdgcn_mfma_f32_16x16x32_bf16(a, b, c, 0, 0, 0);
}

__device__ __forceinline__ f32x4 mfma16k16(s16x4 a, s16x4 b, f32x4 c){
#if __has_builtin(__builtin_amdgcn_mfma_f32_16x16x16bf16_1k)
  return __builtin_amdgcn_mfma_f32_16x16x16bf16_1k(a, b, c, 0, 0, 0);
#else
  asm volatile("v_mfma_f32_16x16x16_bf16 %0, %1, %2, %0\n\ts_nop 7\n\ts_nop 7"
               : "+v"(c) : "v"(a), "v"(b));
  return c;
#endif
}

__device__ __forceinline__ s16x4 pack4(f32x4 a){
  u32x2 u;
  u.x = (unsigned)f2bf(a[0]) | ((unsigned)f2bf(a[1])<<16);
  u.y = (unsigned)f2bf(a[2]) | ((unsigned)f2bf(a[3])<<16);
  return __builtin_bit_cast(s16x4, u);
}

// ---------------- prep: x fp32 -> bf16 ----------------
__global__ void prep_x(const float* __restrict__ x, unsigned short* __restrict__ xb){
  int i = (blockIdx.x*256 + threadIdx.x)*4;
  float4 v = *(const float4*)(x + i);
  unsigned short s0=f2bf(v.x), s1=f2bf(v.y), s2=f2bf(v.z), s3=f2bf(v.w);
  uint2 u; u.x = (unsigned)s0 | ((unsigned)s1<<16); u.y = (unsigned)s2 | ((unsigned)s3<<16);
  *(uint2*)(xb + i) = u;
}

// ---------------- prep: transpose weights to [n][k] bf16 ----------------
__global__ void prep_w(const float* __restrict__ Wq, const float* __restrict__ Wk,
                       const float* __restrict__ Wv, const float* __restrict__ Wp,
                       unsigned short* __restrict__ WT){
  __shared__ float t[64][65];
  const float* W = (blockIdx.z==0)?Wq:(blockIdx.z==1)?Wk:(blockIdx.z==2)?Wv:Wp;
  const int k0 = blockIdx.x*64, n0 = blockIdx.y*64;
  const int c = threadIdx.x&63, rq = threadIdx.x>>6;
  #pragma unroll
  for(int rr=0;rr<16;rr++){
    int kl = rq*16+rr;
    t[kl][c] = W[(size_t)(k0+kl)*DM + n0 + c];
  }
  __syncthreads();
  unsigned short* o = WT + (size_t)blockIdx.z*DM*DM;
  #pragma unroll
  for(int rr=0;rr<16;rr++){
    int nl = rq*16+rr;
    o[(size_t)(n0+nl)*DM + k0 + c] = f2bf(t[c][nl]);
  }
}

// ---------------- QKV projection GEMM ----------------
// z=0: Qs (scaled 1/8) [b][h][p][d]; z=1: K [b][h][p][d];
// z=2: VA — V^T in K16-A-frag-native layout [b][g][nt][p/4][d&15][p&3]
__global__ __launch_bounds__(256) void qkv_kern(const unsigned short* __restrict__ xb,
    const unsigned short* __restrict__ WT,
    unsigned short* __restrict__ Qs, unsigned short* __restrict__ Kk,
    unsigned short* __restrict__ VA){
  const int z = blockIdx.z, h = blockIdx.y;
  const int R0 = blockIdx.x*64;
  const int tid = threadIdx.x;
  const int w = tid>>6, lane = tid&63, m = lane&15, q = lane>>4;
  const unsigned short* Wz = WT + (size_t)z*DM*DM;
  f32x4 acc[4] = {};
  const unsigned short* arow = xb + (size_t)(R0 + w*16 + m)*DM + q*8;
  const unsigned short* brow = Wz + (size_t)(h*64 + m)*DM + q*8;
  for(int k=0;k<DM;k+=32){
    s16x8 A = *(const s16x8*)(arow + k);
    #pragma unroll
    for(int nt=0;nt<4;nt++){
      s16x8 B = *(const s16x8*)(brow + (size_t)nt*16*DM + k);
      acc[nt] = mfma16(A, B, acc[nt]);
    }
  }
  __shared__ float t[64][65];
  const float scale = (z==0) ? 0.125f : 1.0f;
  #pragma unroll
  for(int nt=0;nt<4;nt++)
    #pragma unroll
    for(int r=0;r<4;r++)
      t[w*16 + q*4 + r][nt*16 + m] = acc[nt][r]*scale;
  __syncthreads();
  const int b = R0>>11, p0 = R0&2047;
  if(z<2){
    unsigned short* outp = (z==0)? Qs : Kk;
    int pl = tid>>2, c0 = (tid&3)*16;
    unsigned short vbuf[16];
    #pragma unroll
    for(int i=0;i<16;i++) vbuf[i]=f2bf(t[pl][c0+i]);
    unsigned short* dst = outp + ((size_t)(b*NH+h)*NP + p0+pl)*DH + c0;
    uint4 u0, u1;
    u0.x=(unsigned)vbuf[0]|((unsigned)vbuf[1]<<16);  u0.y=(unsigned)vbuf[2]|((unsigned)vbuf[3]<<16);
    u0.z=(unsigned)vbuf[4]|((unsigned)vbuf[5]<<16);  u0.w=(unsigned)vbuf[6]|((unsigned)vbuf[7]<<16);
    u1.x=(unsigned)vbuf[8]|((unsigned)vbuf[9]<<16);  u1.y=(unsigned)vbuf[10]|((unsigned)vbuf[11]<<16);
    u1.z=(unsigned)vbuf[12]|((unsigned)vbuf[13]<<16);u1.w=(unsigned)vbuf[14]|((unsigned)vbuf[15]<<16);
    *(uint4*)dst = u0; *(uint4*)(dst+8) = u1;
  } else {
    int d = tid>>2, c0 = (tid&3)*16;
    unsigned short* vb = VA + (size_t)b*(8u*4u*(NP/4)*64u)
        + ((size_t)(h*4 + (d>>4))*(NP/4))*64 + (size_t)(d&15)*4;
    #pragma unroll
    for(int grp=0; grp<4; grp++){
      int pl = c0 + grp*4;
      unsigned short v4[4];
      #pragma unroll
      for(int tt=0; tt<4; tt++) v4[tt] = f2bf(t[pl+tt][d]);
      uint2 u; u.x = (unsigned)v4[0] | ((unsigned)v4[1]<<16);
      u.y = (unsigned)v4[2] | ((unsigned)v4[3]<<16);
      *(uint2*)(vb + (size_t)((p0 + pl)>>2)*64) = u;
    }
  }
}

// ---------------- attn sweep 1 (fallback): denominators only --------------
// DO NOT peephole the attn inner loops: r1/r2 showed any perturbation of the
// instruction stream tips the 256-reg knife edge into scratch spills.
// NOTE (r11): fusing the two sweeps is mathematically INVALID — the W2 mix
// couples P-head h with V-head go; two sweeps (or P materialization) forced.
__global__ __launch_bounds__(128,2) void attn1_kern(const unsigned short* __restrict__ Qs,
    const unsigned short* __restrict__ Kk, const float* __restrict__ W1,
    float* __restrict__ Lpart){
  const int bx = blockIdx.x;
  const int c = bx & 7;
  const int b = (bx>>3) & 1;
  const int it = bx>>4;                  // 0..63
  const int tid = threadIdx.x;
  const int iw = tid>>6, lane = tid&63, m = lane&15, q = lane>>4;
  const int i0 = it*32 + iw*16;
  const int cb = c*(NP/JC1);

  float w1[8][8];
  #pragma unroll
  for(int h=0;h<8;h++)
    #pragma unroll
    for(int g=0;g<8;g++) w1[h][g]=W1[h*8+g];

  const unsigned short* Qb = Qs + (size_t)b*NH*NP*DH;
  const unsigned short* Kb = Kk + (size_t)b*NH*NP*DH;

  s16x8 Qf[8][2];
  #pragma unroll
  for(int h=0;h<8;h++){
    const unsigned short* qp = Qb + ((size_t)h*NP + i0 + m)*DH + q*8;
    Qf[h][0] = *(const s16x8*)(qp);
    Qf[h][1] = *(const s16x8*)(qp + 32);
  }

  float lacc[8] = {};
  for(int jt=0; jt<NT1; jt++){
    const int j0 = cb + jt*16;
    s16x8 K[8][2];
    #pragma unroll
    for(int h=0;h<8;h++){
      const unsigned short* kp = Kb + ((size_t)h*NP + j0 + m)*DH + q*8;
      K[h][0] = *(const s16x8*)(kp);
      K[h][1] = *(const s16x8*)(kp + 32);
    }
    f32x4 s1[8] = {};
    #pragma unroll
    for(int h=0;h<8;h++){
      f32x4 z = {};
      z = mfma16(K[h][0], Qf[h][0], z);       // A=K (m=j), B=Q (n=i) -> S^T
      f32x4 Sh = mfma16(K[h][1], Qf[h][1], z);
      #pragma unroll
      for(int g=0;g<8;g++) s1[g] += Sh*w1[h][g];
    }
    #pragma unroll
    for(int g=0;g<8;g++)
      #pragma unroll
      for(int r=0;r<4;r++) lacc[g] += __expf(s1[g][r]);
  }
  #pragma unroll
  for(int g=0;g<8;g++){
    float v = lacc[g];
    v += __shfl_xor(v,16); v += __shfl_xor(v,32);
    lacc[g] = v;
  }
  if(lane < 16){
    #pragma unroll
    for(int g=0;g<8;g++)
      Lpart[(((size_t)c*NB + b)*NH + g)*NP + i0 + lane] = lacc[g];
  }
}

// ---------------- attn sweep 1 (P-store, per-h K-rotated) -----------------
// r10 structure + r17 change: Pm stores are PLAIN (nt hint dropped). The nt
// hint pushed P lines toward memory, so attn2p's first pass re-read ~134 MB
// from HBM (r16 FETCH 141 MB). Plain stores leave Pm L2/L3-resident
// (134 MB < 256 MB L3) for attn2p, which launches immediately after.
__global__ __launch_bounds__(128,2) void attn1p_kern(const unsigned short* __restrict__ Qs,
    const unsigned short* __restrict__ Kk, const float* __restrict__ W1,
    float* __restrict__ Lpart, unsigned short* __restrict__ Pm){
  const int bx = blockIdx.x;
  const int c = bx & 7;
  const int b = (bx>>3) & 1;
  const int it = bx>>4;                  // 0..63
  const int tid = threadIdx.x;
  const int iw = tid>>6, lane = tid&63, m = lane&15, q = lane>>4;
  const int i0 = it*32 + iw*16;
  const int cb = c*(NP/JC1);

  float w1[8][8];
  #pragma unroll
  for(int h=0;h<8;h++)
    #pragma unroll
    for(int g=0;g<8;g++) w1[h][g]=W1[h*8+g];

  const unsigned short* Qb = Qs + (size_t)b*NH*NP*DH;
  const unsigned short* Kb = Kk + (size_t)b*NH*NP*DH;
  unsigned short* Pw = Pm + (((size_t)bx*2 + iw)*16)*8*64*4;

  s16x8 Qf[8][2];
  #pragma unroll
  for(int h=0;h<8;h++){
    const unsigned short* qp = Qb + ((size_t)h*NP + i0 + m)*DH + q*8;
    Qf[h][0] = *(const s16x8*)(qp);
    Qf[h][1] = *(const s16x8*)(qp + 32);
  }

  // preload K tile for jt=0
  s16x8 K[8][2];
  #pragma unroll
  for(int h=0;h<8;h++){
    const unsigned short* kp = Kb + ((size_t)h*NP + cb + m)*DH + q*8;
    K[h][0] = *(const s16x8*)(kp);
    K[h][1] = *(const s16x8*)(kp + 32);
  }

  float lacc[8] = {};
  for(int jt=0; jt<NT1; jt++){
    const int j1 = cb + (jt+1)*16;
    f32x4 s1[8] = {};
    #pragma unroll
    for(int h=0;h<8;h++){
      f32x4 z = {};
      z = mfma16(K[h][0], Qf[h][0], z);       // A=K (m=j), B=Q (n=i) -> S^T
      f32x4 Sh = mfma16(K[h][1], Qf[h][1], z);
      // K[h] dead now: reload in place with next jt's tile
      if(jt+1 < NT1){
        const unsigned short* kp = Kb + ((size_t)h*NP + j1 + m)*DH + q*8;
        K[h][0] = *(const s16x8*)(kp);
        K[h][1] = *(const s16x8*)(kp + 32);
      }
      #pragma unroll
      for(int g=0;g<8;g++) s1[g] += Sh*w1[h][g];
    }
    unsigned short* Pjt = Pw + (size_t)jt*8*64*4;
    #pragma unroll
    for(int g=0;g<8;g++){
      f32x4 e;
      #pragma unroll
      for(int r=0;r<4;r++){ e[r] = __expf(s1[g][r]); lacc[g] += e[r]; }
      s16x4 pk = pack4(e);
      *(s16x4*)(Pjt + ((size_t)g*64 + lane)*4) = pk;
    }
  }
  #pragma unroll
  for(int g=0;g<8;g++){
    float v = lacc[g];
    v += __shfl_xor(v,16); v += __shfl_xor(v,32);
    lacc[g] = v;
  }
  if(lane < 16){
    #pragma unroll
    for(int g=0;g<8;g++)
      Lpart[(((size_t)c*NB + b)*NH + g)*NP + i0 + lane] = lacc[g];
  }
}

// ---------------- attn sweep 2 (fallback): full recompute -----------------
__global__ __launch_bounds__(128,2) void attn2_kern(const unsigned short* __restrict__ Qs,
    const unsigned short* __restrict__ Kk, const unsigned short* __restrict__ VA,
    const float* __restrict__ W1, const float* __restrict__ W2,
    const float* __restrict__ Lpart, unsigned short* __restrict__ Opart){
  const int bx = blockIdx.x;
  const int c = bx & 7;
  const int b = (bx>>3) & 1;
  const int it = bx>>4;
  const int tid = threadIdx.x;
  const int iw = tid>>6, lane = tid&63, m = lane&15, q = lane>>4;
  const int i0 = it*32 + iw*16;
  const int cb = c*(NP/JC2);

  __shared__ unsigned short Osh[32*OPITCH];

  float w1[8][8], w2[8][8];
  #pragma unroll
  for(int h=0;h<8;h++)
    #pragma unroll
    for(int g=0;g<8;g++){ w1[h][g]=W1[h*8+g]; w2[h][g]=W2[h*8+g]; }

  const unsigned short* Qb = Qs + (size_t)b*NH*NP*DH;
  const unsigned short* Kb = Kk + (size_t)b*NH*NP*DH;
  const unsigned short* VAb = VA + (size_t)b*(8u*4u*(NP/4)*64u);

  {
    const int qr = lane>>2, qc = (lane&3)*16;
    #pragma unroll
    for(int h=0;h<8;h++){
      const unsigned short* src = Qb + ((size_t)h*NP + i0 + qr)*DH + qc;
      unsigned short* dst = &Osh[(size_t)(iw*16+qr)*OPITCH + h*64 + qc];
      *(u32x4*)dst = *(const u32x4*)src;
      *(u32x4*)(dst+8) = *(const u32x4*)(src+8);
    }
  }

  float rl[8];
  #pragma unroll
  for(int g=0;g<8;g++){
    float v = 0.f;
    #pragma unroll
    for(int cc=0;cc<JC1;cc++)
      v += Lpart[(((size_t)cc*NB + b)*NH + g)*NP + i0 + m];
    rl[g] = 1.0f/v;
  }

  f32x4 Oacc[8][4] = {};
  const unsigned short* QL = &Osh[(size_t)(iw*16+m)*OPITCH];

  for(int jt=0; jt<NT2; jt++){
    const int j0 = cb + jt*16;
    s16x8 K[8][2];
    #pragma unroll
    for(int h=0;h<8;h++){
      const unsigned short* kp = Kb + ((size_t)h*NP + j0 + m)*DH + q*8;
      K[h][0] = *(const s16x8*)(kp);
      K[h][1] = *(const s16x8*)(kp + 32);
    }
    f32x4 s1[8] = {};
    #pragma unroll
    for(int h=0;h<8;h++){
      s16x8 q0 = *(const s16x8*)(QL + h*64 + q*8);
      s16x8 q1 = *(const s16x8*)(QL + h*64 + 32 + q*8);
      f32x4 z = {};
      z = mfma16(K[h][0], q0, z);
      f32x4 Sh = mfma16(K[h][1], q1, z);
      #pragma unroll
      for(int g=0;g<8;g++) s1[g] += Sh*w1[h][g];
    }
    s16x4 Vf[8][4];
    const size_t jq = (size_t)(j0>>2) + q;
    #pragma unroll
    for(int g=0;g<8;g++)
      #pragma unroll
      for(int nt=0;nt<4;nt++)
        Vf[g][nt] = *(const s16x4*)(VAb + ((((size_t)g*4+nt)*(NP/4) + jq)<<6) + (m<<2));
    #pragma unroll
    for(int g=0;g<8;g++){
      #pragma unroll
      for(int r=0;r<4;r++) s1[g][r] = __expf(s1[g][r]);
      s1[g] *= rl[g];
    }
    s16x4 A2[8];
    #pragma unroll
    for(int go=0;go<8;go++){
      f32x4 a = s1[0]*w2[0][go];
      #pragma unroll
      for(int h=1;h<8;h++) a += s1[h]*w2[h][go];
      A2[go] = pack4(a);
    }
    #pragma unroll
    for(int g=0;g<8;g++)
      #pragma unroll
      for(int nt=0;nt<4;nt++)
        Oacc[g][nt] = mfma16k16(Vf[g][nt], A2[g], Oacc[g][nt]);
  }

  #pragma unroll
  for(int g=0;g<8;g++)
    #pragma unroll
    for(int nt=0;nt<4;nt++){
      s16x4 pk = pack4(Oacc[g][nt]);
      *(s16x4*)(&Osh[(size_t)(iw*16 + m)*OPITCH + g*64 + nt*16 + 4*q]) = pk;
    }
  __syncthreads();
  unsigned short* Oc = Opart + (size_t)c*NROWS*DM;
  const size_t R0 = (size_t)b*NP + (size_t)it*32;
  #pragma unroll
  for(int t=0;t<16;t++){
    int idx = t*128 + tid;
    int row = idx>>6, c8 = idx&63;
    u32x4 v = *(const u32x4*)(&Osh[(size_t)row*OPITCH + c8*8]);
    __builtin_nontemporal_store(v, (u32x4*)(Oc + (R0 + row)*DM + c8*8));
  }
}

// ---------------- attn sweep 2 (P-load, go-split, deep-rotated) -----------
// r16 verified: 2-step Pf+Vf pipeline, go-half, VGPR 120, PLAIN Pm loads
// (nt hint dropped -> +23 us vs r12). r13/r14 measured: go-quarter loses —
// every extra Pm pass costs more HBM time than added occupancy recovers.
__global__ __launch_bounds__(128,2) void attn2p_kern(const unsigned short* __restrict__ Pm,
    const unsigned short* __restrict__ VA, const float* __restrict__ W2,
    const float* __restrict__ Lpart, unsigned short* __restrict__ Opart){
  const int bx = blockIdx.x;
  const int go0 = blockIdx.y;            // 0/1 -> output heads go0*4..go0*4+3
  const int c = bx & 7;                  // chunk, pinned to XCD
  const int b = (bx>>3) & 1;
  const int it = bx>>4;                  // 0..63
  const int tid = threadIdx.x;
  const int iw = tid>>6, lane = tid&63, m = lane&15, q = lane>>4;
  const int i0 = it*32 + iw*16;
  const int cb = c*(NP/JC2);

  __shared__ unsigned short Osh[32*SPITCH];   // 32 x 256-col slab epilogue

  float w2[8][4];
  #pragma unroll
  for(int h=0;h<8;h++)
    #pragma unroll
    for(int g=0;g<4;g++) w2[h][g]=W2[h*8 + go0*4 + g];

  const unsigned short* VAb = VA + (size_t)b*(8u*4u*(NP/4)*64u);
  const unsigned short* Pw = Pm + (((size_t)bx*2 + iw)*16)*8*64*4;

  s16x4 PfA[8], PfB[8], VfA[4][4], VfB[4][4];

  // prologue: load jt=0 fragments (overlaps the rl gather below)
  #pragma unroll
  for(int g=0;g<8;g++)
    PfA[g] = *(const s16x4*)(Pw + ((size_t)g*64 + lane)*4);
  {
    const size_t jq0 = (size_t)(cb>>2) + q;
    #pragma unroll
    for(int g=0;g<4;g++){
      const int gh = go0*4 + g;
      #pragma unroll
      for(int nt=0;nt<4;nt++)
        VfA[g][nt] = *(const s16x4*)(VAb + ((((size_t)gh*4+nt)*(NP/4) + jq0)<<6) + (m<<2));
    }
  }

  // 1/l for this wave's 16 columns (i = i0 + lane&15); all 8 input heads
  float rl[8];
  #pragma unroll
  for(int g=0;g<8;g++){
    float v = 0.f;
    #pragma unroll
    for(int cc=0;cc<JC1;cc++)
      v += Lpart[(((size_t)cc*NB + b)*NH + g)*NP + i0 + m];
    rl[g] = 1.0f/v;
  }

  f32x4 Oacc[4][4] = {};

  for(int jt2=0; jt2<NT2; jt2+=2){
    // ---- even step: consume A (jt2), prefetch B (jt2+1, always valid) ----
    {
      f32x4 s1[8];
      #pragma unroll
      for(int g=0;g<8;g++){
        u32x2 u = __builtin_bit_cast(u32x2, PfA[g]);
        f32x4 p;
        p[0] = __builtin_bit_cast(float, u.x<<16);
        p[1] = __builtin_bit_cast(float, u.x & 0xffff0000u);
        p[2] = __builtin_bit_cast(float, u.y<<16);
        p[3] = __builtin_bit_cast(float, u.y & 0xffff0000u);
        s1[g] = p * rl[g];
      }
      const unsigned short* Pn = Pw + (size_t)(jt2+1)*8*64*4;
      #pragma unroll
      for(int g=0;g<8;g++)
        PfB[g] = *(const s16x4*)(Pn + ((size_t)g*64 + lane)*4);
      const size_t jqn = (size_t)((cb + (jt2+1)*16)>>2) + q;
      #pragma unroll
      for(int g=0;g<4;g++){
        const int gh = go0*4 + g;
        #pragma unroll
        for(int nt=0;nt<4;nt++)
          VfB[g][nt] = *(const s16x4*)(VAb + ((((size_t)gh*4+nt)*(NP/4) + jqn)<<6) + (m<<2));
      }
      #pragma unroll
      for(int g=0;g<4;g++){
        f32x4 a = s1[0]*w2[0][g];
        #pragma unroll
        for(int h=1;h<8;h++) a += s1[h]*w2[h][g];
        s16x4 A2 = pack4(a);
        #pragma unroll
        for(int nt=0;nt<4;nt++)
          Oacc[g][nt] = mfma16k16(VfA[g][nt], A2, Oacc[g][nt]);
      }
    }
    // ---- odd step: consume B (jt2+1), prefetch A (jt2+2 if valid) ----
    {
      f32x4 s1[8];
      #pragma unroll
      for(int g=0;g<8;g++){
        u32x2 u = __builtin_bit_cast(u32x2, PfB[g]);
        f32x4 p;
        p[0] = __builtin_bit_cast(float, u.x<<16);
        p[1] = __builtin_bit_cast(float, u.x & 0xffff0000u);
        p[2] = __builtin_bit_cast(float, u.y<<16);
        p[3] = __builtin_bit_cast(float, u.y & 0xffff0000u);
        s1[g] = p * rl[g];
      }
      if(jt2+2 < NT2){
        const unsigned short* Pn = Pw + (size_t)(jt2+2)*8*64*4;
        #pragma unroll
        for(int g=0;g<8;g++)
          PfA[g] = *(const s16x4*)(Pn + ((size_t)g*64 + lane)*4);
        const size_t jqn = (size_t)((cb + (jt2+2)*16)>>2) + q;
        #pragma unroll
        for(int g=0;g<4;g++){
          const int gh = go0*4 + g;
          #pragma unroll
          for(int nt=0;nt<4;nt++)
            VfA[g][nt] = *(const s16x4*)(VAb + ((((size_t)gh*4+nt)*(NP/4) + jqn)<<6) + (m<<2));
        }
      }
      #pragma unroll
      for(int g=0;g<4;g++){
        f32x4 a = s1[0]*w2[0][g];
        #pragma unroll
        for(int h=1;h<8;h++) a += s1[h]*w2[h][g];
        s16x4 A2 = pack4(a);
        #pragma unroll
        for(int nt=0;nt<4;nt++)
          Oacc[g][nt] = mfma16k16(VfB[g][nt], A2, Oacc[g][nt]);
      }
    }
  }

  // epilogue: 32x256 slab via LDS, coalesced nontemporal stores
  #pragma unroll
  for(int g=0;g<4;g++)
    #pragma unroll
    for(int nt=0;nt<4;nt++){
      s16x4 pk = pack4(Oacc[g][nt]);
      *(s16x4*)(&Osh[(size_t)(iw*16 + m)*SPITCH + g*64 + nt*16 + 4*q]) = pk;
    }
  __syncthreads();
  unsigned short* Oc = Opart + (size_t)c*NROWS*DM;
  const size_t R0 = (size_t)b*NP + (size_t)it*32;
  const int col0 = go0*256;
  #pragma unroll
  for(int t=0;t<8;t++){
    int idx = t*128 + tid;
    int row = idx>>5, c8 = idx&31;
    u32x4 v = *(const u32x4*)(&Osh[(size_t)row*SPITCH + c8*8]);
    __builtin_nontemporal_store(v, (u32x4*)(Oc + (R0 + row)*DM + col0 + c8*8));
  }
}

// ---------------- chunk reduction: Of = sum_c Opart_c (bf16, f32 accum) ----
__global__ __launch_bounds__(256) void reduce_kern(const unsigned short* __restrict__ Op,
    unsigned short* __restrict__ Of){
  const size_t i = ((size_t)blockIdx.x*256 + threadIdx.x)*8;
  float acc[8] = {};
  #pragma unroll
  for(int cc=0;cc<JC2;cc++){
    u32x4 v = *(const u32x4*)(Op + (size_t)cc*NROWS*DM + i);
    #pragma unroll
    for(int e=0;e<4;e++){
      unsigned u = v[e];
      acc[2*e]   += __builtin_bit_cast(float, u<<16);
      acc[2*e+1] += __builtin_bit_cast(float, u & 0xffff0000u);
    }
  }
  u32x4 o;
  #pragma unroll
  for(int e=0;e<4;e++)
    o[e] = (unsigned)f2bf(acc[2*e]) | ((unsigned)f2bf(acc[2*e+1])<<16);
  *(u32x4*)(Of + i) = o;
}

// ---------------- output projection: out = Of @ Wproj (single pass) -------
__global__ __launch_bounds__(256) void oproj_kern(const unsigned short* __restrict__ Of,
    const unsigned short* __restrict__ WT, float* __restrict__ out){
  const int nb = blockIdx.y;
  const int R0 = blockIdx.x*64;
  const int tid = threadIdx.x;
  const int w = tid>>6, lane = tid&63, m = lane&15, q = lane>>4;
  const unsigned short* Wp = WT + (size_t)3*DM*DM;
  f32x4 acc[4] = {};
  const unsigned short* brow = Wp + (size_t)(nb*64 + m)*DM + q*8;
  const unsigned short* arow = Of + (size_t)(R0 + w*16 + m)*DM + q*8;
  for(int k=0;k<DM;k+=32){
    s16x8 A = *(const s16x8*)(arow + k);
    #pragma unroll
    for(int nt=0;nt<4;nt++){
      s16x8 B = *(const s16x8*)(brow + (size_t)nt*16*DM + k);
      acc[nt] = mfma16(A, B, acc[nt]);
    }
  }
  #pragma unroll
  for(int nt=0;nt<4;nt++)
    #pragma unroll
    for(int r=0;r<4;r++)
      out[(size_t)(R0 + w*16 + q*4 + r)*DM + nb*64 + nt*16 + m] = acc[nt][r];
}

extern "C" void kernel_launch(void* const* d_in, const int* in_sizes, int n_in,
                              void* d_out, int out_size, void* d_ws, size_t ws_size,
                              hipStream_t stream){
  (void)in_sizes; (void)n_in; (void)out_size;
  const float* x  = (const float*)d_in[0];
  const float* Wq = (const float*)d_in[1];
  const float* Wk = (const float*)d_in[2];
  const float* Wv = (const float*)d_in[3];
  const float* W1 = (const float*)d_in[4];
  const float* W2 = (const float*)d_in[5];
  const float* Wp = (const float*)d_in[6];

  char* ws = (char*)d_ws;
  unsigned short* xb = (unsigned short*)ws;  ws += (size_t)NROWS*DM*2;     // 4 MB
  unsigned short* WT = (unsigned short*)ws;  ws += (size_t)4*DM*DM*2;      // 2 MB
  unsigned short* Qs = (unsigned short*)ws;  ws += (size_t)NB*NH*NP*DH*2;  // 4 MB
  unsigned short* Kk = (unsigned short*)ws;  ws += (size_t)NB*NH*NP*DH*2;  // 4 MB
  unsigned short* VA = (unsigned short*)ws;  ws += (size_t)NB*NH*DH*NP*2;  // 4 MB
  float*          Lp = (float*)ws;           ws += (size_t)JC1*NB*NH*NP*4; // 2 MB
  unsigned short* Op = (unsigned short*)ws;  ws += (size_t)JC2*NROWS*DM*2; // 32 MB
  unsigned short* Pm = (unsigned short*)ws;  // 128 MiB if it fits
  const size_t pm_bytes = (size_t)1024*2*16*8*64*4*2;  // [bx][iw][jt][g][lane]x4
  const size_t need = (size_t)((char*)Pm - (char*)d_ws) + pm_bytes;
  unsigned short* Of = xb;  // alias: xb is dead after qkv_kern

  prep_x<<<NROWS*DM/1024, 256, 0, stream>>>(x, xb);
  prep_w<<<dim3(8,8,4), 256, 0, stream>>>(Wq, Wk, Wv, Wp, WT);
  qkv_kern<<<dim3(64,8,3), 256, 0, stream>>>(xb, WT, Qs, Kk, VA);
  if(ws_size >= need){
    attn1p_kern<<<dim3(1024), 128, 0, stream>>>(Qs, Kk, W1, Lp, Pm);
    attn2p_kern<<<dim3(1024,2), 128, 0, stream>>>(Pm, VA, W2, Lp, Op);
  } else {
    attn1_kern<<<dim3(1024), 128, 0, stream>>>(Qs, Kk, W1, Lp);
    attn2_kern<<<dim3(1024), 128, 0, stream>>>(Qs, Kk, VA, W1, W2, Lp, Op);
  }
  reduce_kern<<<dim3(NROWS*DM/2048), 256, 0, stream>>>(Op, Of);
  oproj_kern<<<dim3(64,8), 256, 0, stream>>>(Of, WT, (float*)d_out);
}

// Round 18
// 295.584 us; speedup vs baseline: 1.1860x; 1.0226x over previous
//
#include <hip/hip_runtime.h>
#include <hip/hip_bf16.h>

#define DM 512
#define DH 64
#define NH 8
#define NP 2048
#define NB 2
#define NROWS (NB*NP)
#define JC1 8            // attn1 j-chunks (chunk = 256 j, 16 jt of 16)
#define JC2 8            // attn2 j-chunks (chunk = 256 j, 16 jt of 16)
#define NT1 (NP/JC1/16)  // 16
#define NT2 (NP/JC2/16)  // 16
#define OPITCH 520       // LDS pitch (shorts) for 512-wide tiles
#define SPITCH 264       // LDS pitch (shorts) for 256-wide slab (attn2p epilogue)

typedef short s16x8 __attribute__((ext_vector_type(8)));
typedef short s16x4 __attribute__((ext_vector_type(4)));
typedef float f32x4 __attribute__((ext_vector_type(4)));
typedef unsigned int u32x4 __attribute__((ext_vector_type(4)));
typedef unsigned int u32x2 __attribute__((ext_vector_type(2)));

__device__ __forceinline__ unsigned short f2bf(float f){
  __hip_bfloat16 h = __float2bfloat16(f);
  return __builtin_bit_cast(unsigned short, h);
}

__device__ __forceinline__ f32x4 mfma16(s16x8 a, s16x8 b, f32x4 c){
  return __builtin_amdgcn_mfma_f32_16x16x32_bf16(a, b, c, 0, 0, 0);
}

__device__ __forceinline__ f32x4 mfma16k16(s16x4 a, s16x4 b, f32x4 c){
#if __has_builtin(__builtin_amdgcn_mfma_f32_16x16x16bf16_1k)
  return __builtin_amdgcn_mfma_f32_16x16x16bf16_1k(a, b, c, 0, 0, 0);
#else
  asm volatile("v_mfma_f32_16x16x16_bf16 %0, %1, %2, %0\n\ts_nop 7\n\ts_nop 7"
               : "+v"(c) : "v"(a), "v"(b));
  return c;
#endif
}

__device__ __forceinline__ s16x4 pack4(f32x4 a){
  u32x2 u;
  u.x = (unsigned)f2bf(a[0]) | ((unsigned)f2bf(a[1])<<16);
  u.y = (unsigned)f2bf(a[2]) | ((unsigned)f2bf(a[3])<<16);
  return __builtin_bit_cast(s16x4, u);
}

// ---------------- prep: x fp32 -> bf16 ----------------
__global__ void prep_x(const float* __restrict__ x, unsigned short* __restrict__ xb){
  int i = (blockIdx.x*256 + threadIdx.x)*4;
  float4 v = *(const float4*)(x + i);
  unsigned short s0=f2bf(v.x), s1=f2bf(v.y), s2=f2bf(v.z), s3=f2bf(v.w);
  uint2 u; u.x = (unsigned)s0 | ((unsigned)s1<<16); u.y = (unsigned)s2 | ((unsigned)s3<<16);
  *(uint2*)(xb + i) = u;
}

// ---------------- prep: transpose weights to [n][k] bf16 ----------------
__global__ void prep_w(const float* __restrict__ Wq, const float* __restrict__ Wk,
                       const float* __restrict__ Wv, const float* __restrict__ Wp,
                       unsigned short* __restrict__ WT){
  __shared__ float t[64][65];
  const float* W = (blockIdx.z==0)?Wq:(blockIdx.z==1)?Wk:(blockIdx.z==2)?Wv:Wp;
  const int k0 = blockIdx.x*64, n0 = blockIdx.y*64;
  const int c = threadIdx.x&63, rq = threadIdx.x>>6;
  #pragma unroll
  for(int rr=0;rr<16;rr++){
    int kl = rq*16+rr;
    t[kl][c] = W[(size_t)(k0+kl)*DM + n0 + c];
  }
  __syncthreads();
  unsigned short* o = WT + (size_t)blockIdx.z*DM*DM;
  #pragma unroll
  for(int rr=0;rr<16;rr++){
    int nl = rq*16+rr;
    o[(size_t)(n0+nl)*DM + k0 + c] = f2bf(t[c][nl]);
  }
}

// ---------------- QKV projection GEMM ----------------
// z=0: Qs (scaled 1/8) [b][h][p][d]; z=1: K [b][h][p][d];
// z=2: VA — V^T in K16-A-frag-native layout [b][g][nt][p/4][d&15][p&3]
__global__ __launch_bounds__(256) void qkv_kern(const unsigned short* __restrict__ xb,
    const unsigned short* __restrict__ WT,
    unsigned short* __restrict__ Qs, unsigned short* __restrict__ Kk,
    unsigned short* __restrict__ VA){
  const int z = blockIdx.z, h = blockIdx.y;
  const int R0 = blockIdx.x*64;
  const int tid = threadIdx.x;
  const int w = tid>>6, lane = tid&63, m = lane&15, q = lane>>4;
  const unsigned short* Wz = WT + (size_t)z*DM*DM;
  f32x4 acc[4] = {};
  const unsigned short* arow = xb + (size_t)(R0 + w*16 + m)*DM + q*8;
  const unsigned short* brow = Wz + (size_t)(h*64 + m)*DM + q*8;
  for(int k=0;k<DM;k+=32){
    s16x8 A = *(const s16x8*)(arow + k);
    #pragma unroll
    for(int nt=0;nt<4;nt++){
      s16x8 B = *(const s16x8*)(brow + (size_t)nt*16*DM + k);
      acc[nt] = mfma16(A, B, acc[nt]);
    }
  }
  __shared__ float t[64][65];
  const float scale = (z==0) ? 0.125f : 1.0f;
  #pragma unroll
  for(int nt=0;nt<4;nt++)
    #pragma unroll
    for(int r=0;r<4;r++)
      t[w*16 + q*4 + r][nt*16 + m] = acc[nt][r]*scale;
  __syncthreads();
  const int b = R0>>11, p0 = R0&2047;
  if(z<2){
    unsigned short* outp = (z==0)? Qs : Kk;
    int pl = tid>>2, c0 = (tid&3)*16;
    unsigned short vbuf[16];
    #pragma unroll
    for(int i=0;i<16;i++) vbuf[i]=f2bf(t[pl][c0+i]);
    unsigned short* dst = outp + ((size_t)(b*NH+h)*NP + p0+pl)*DH + c0;
    uint4 u0, u1;
    u0.x=(unsigned)vbuf[0]|((unsigned)vbuf[1]<<16);  u0.y=(unsigned)vbuf[2]|((unsigned)vbuf[3]<<16);
    u0.z=(unsigned)vbuf[4]|((unsigned)vbuf[5]<<16);  u0.w=(unsigned)vbuf[6]|((unsigned)vbuf[7]<<16);
    u1.x=(unsigned)vbuf[8]|((unsigned)vbuf[9]<<16);  u1.y=(unsigned)vbuf[10]|((unsigned)vbuf[11]<<16);
    u1.z=(unsigned)vbuf[12]|((unsigned)vbuf[13]<<16);u1.w=(unsigned)vbuf[14]|((unsigned)vbuf[15]<<16);
    *(uint4*)dst = u0; *(uint4*)(dst+8) = u1;
  } else {
    int d = tid>>2, c0 = (tid&3)*16;
    unsigned short* vb = VA + (size_t)b*(8u*4u*(NP/4)*64u)
        + ((size_t)(h*4 + (d>>4))*(NP/4))*64 + (size_t)(d&15)*4;
    #pragma unroll
    for(int grp=0; grp<4; grp++){
      int pl = c0 + grp*4;
      unsigned short v4[4];
      #pragma unroll
      for(int tt=0; tt<4; tt++) v4[tt] = f2bf(t[pl+tt][d]);
      uint2 u; u.x = (unsigned)v4[0] | ((unsigned)v4[1]<<16);
      u.y = (unsigned)v4[2] | ((unsigned)v4[3]<<16);
      *(uint2*)(vb + (size_t)((p0 + pl)>>2)*64) = u;
    }
  }
}

// ---------------- attn sweep 1 (fallback): denominators only --------------
// DO NOT peephole the attn inner loops: r1/r2 showed any perturbation of the
// instruction stream tips the 256-reg knife edge into scratch spills.
// NOTE (r11): fusing the two sweeps is mathematically INVALID — the W2 mix
// couples P-head h with V-head go; two sweeps (or P materialization) forced.
__global__ __launch_bounds__(128,2) void attn1_kern(const unsigned short* __restrict__ Qs,
    const unsigned short* __restrict__ Kk, const float* __restrict__ W1,
    float* __restrict__ Lpart){
  const int bx = blockIdx.x;
  const int c = bx & 7;
  const int b = (bx>>3) & 1;
  const int it = bx>>4;                  // 0..63
  const int tid = threadIdx.x;
  const int iw = tid>>6, lane = tid&63, m = lane&15, q = lane>>4;
  const int i0 = it*32 + iw*16;
  const int cb = c*(NP/JC1);

  float w1[8][8];
  #pragma unroll
  for(int h=0;h<8;h++)
    #pragma unroll
    for(int g=0;g<8;g++) w1[h][g]=W1[h*8+g];

  const unsigned short* Qb = Qs + (size_t)b*NH*NP*DH;
  const unsigned short* Kb = Kk + (size_t)b*NH*NP*DH;

  s16x8 Qf[8][2];
  #pragma unroll
  for(int h=0;h<8;h++){
    const unsigned short* qp = Qb + ((size_t)h*NP + i0 + m)*DH + q*8;
    Qf[h][0] = *(const s16x8*)(qp);
    Qf[h][1] = *(const s16x8*)(qp + 32);
  }

  float lacc[8] = {};
  for(int jt=0; jt<NT1; jt++){
    const int j0 = cb + jt*16;
    s16x8 K[8][2];
    #pragma unroll
    for(int h=0;h<8;h++){
      const unsigned short* kp = Kb + ((size_t)h*NP + j0 + m)*DH + q*8;
      K[h][0] = *(const s16x8*)(kp);
      K[h][1] = *(const s16x8*)(kp + 32);
    }
    f32x4 s1[8] = {};
    #pragma unroll
    for(int h=0;h<8;h++){
      f32x4 z = {};
      z = mfma16(K[h][0], Qf[h][0], z);       // A=K (m=j), B=Q (n=i) -> S^T
      f32x4 Sh = mfma16(K[h][1], Qf[h][1], z);
      #pragma unroll
      for(int g=0;g<8;g++) s1[g] += Sh*w1[h][g];
    }
    #pragma unroll
    for(int g=0;g<8;g++)
      #pragma unroll
      for(int r=0;r<4;r++) lacc[g] += __expf(s1[g][r]);
  }
  #pragma unroll
  for(int g=0;g<8;g++){
    float v = lacc[g];
    v += __shfl_xor(v,16); v += __shfl_xor(v,32);
    lacc[g] = v;
  }
  if(lane < 16){
    #pragma unroll
    for(int g=0;g<8;g++)
      Lpart[(((size_t)c*NB + b)*NH + g)*NP + i0 + lane] = lacc[g];
  }
}

// ---------------- attn sweep 1 (P-store, per-h K-rotated, 16B pairs) ------
// r10 structure + r17 plain stores + r18: adjacent g-pairs packed into one
// 16B store (layout [jt][g/2][lane][8]) — halves the P-path VMEM issue
// count; 16B/lane is the coalescing sweet spot. Math bit-identical.
__global__ __launch_bounds__(128,2) void attn1p_kern(const unsigned short* __restrict__ Qs,
    const unsigned short* __restrict__ Kk, const float* __restrict__ W1,
    float* __restrict__ Lpart, unsigned short* __restrict__ Pm){
  const int bx = blockIdx.x;
  const int c = bx & 7;
  const int b = (bx>>3) & 1;
  const int it = bx>>4;                  // 0..63
  const int tid = threadIdx.x;
  const int iw = tid>>6, lane = tid&63, m = lane&15, q = lane>>4;
  const int i0 = it*32 + iw*16;
  const int cb = c*(NP/JC1);

  float w1[8][8];
  #pragma unroll
  for(int h=0;h<8;h++)
    #pragma unroll
    for(int g=0;g<8;g++) w1[h][g]=W1[h*8+g];

  const unsigned short* Qb = Qs + (size_t)b*NH*NP*DH;
  const unsigned short* Kb = Kk + (size_t)b*NH*NP*DH;
  unsigned short* Pw = Pm + (((size_t)bx*2 + iw)*16)*8*64*4;

  s16x8 Qf[8][2];
  #pragma unroll
  for(int h=0;h<8;h++){
    const unsigned short* qp = Qb + ((size_t)h*NP + i0 + m)*DH + q*8;
    Qf[h][0] = *(const s16x8*)(qp);
    Qf[h][1] = *(const s16x8*)(qp + 32);
  }

  // preload K tile for jt=0
  s16x8 K[8][2];
  #pragma unroll
  for(int h=0;h<8;h++){
    const unsigned short* kp = Kb + ((size_t)h*NP + cb + m)*DH + q*8;
    K[h][0] = *(const s16x8*)(kp);
    K[h][1] = *(const s16x8*)(kp + 32);
  }

  float lacc[8] = {};
  for(int jt=0; jt<NT1; jt++){
    const int j1 = cb + (jt+1)*16;
    f32x4 s1[8] = {};
    #pragma unroll
    for(int h=0;h<8;h++){
      f32x4 z = {};
      z = mfma16(K[h][0], Qf[h][0], z);       // A=K (m=j), B=Q (n=i) -> S^T
      f32x4 Sh = mfma16(K[h][1], Qf[h][1], z);
      // K[h] dead now: reload in place with next jt's tile
      if(jt+1 < NT1){
        const unsigned short* kp = Kb + ((size_t)h*NP + j1 + m)*DH + q*8;
        K[h][0] = *(const s16x8*)(kp);
        K[h][1] = *(const s16x8*)(kp + 32);
      }
      #pragma unroll
      for(int g=0;g<8;g++) s1[g] += Sh*w1[h][g];
    }
    unsigned short* Pjt = Pw + (size_t)jt*8*64*4;
    u32x2 pkE = {};
    #pragma unroll
    for(int g=0;g<8;g++){
      f32x4 e;
      #pragma unroll
      for(int r=0;r<4;r++){ e[r] = __expf(s1[g][r]); lacc[g] += e[r]; }
      u32x2 pk = __builtin_bit_cast(u32x2, pack4(e));
      if((g&1)==0){
        pkE = pk;
      } else {
        u32x4 pp; pp[0]=pkE.x; pp[1]=pkE.y; pp[2]=pk.x; pp[3]=pk.y;
        *(u32x4*)(Pjt + (((size_t)(g>>1))*64 + lane)*8) = pp;
      }
    }
  }
  #pragma unroll
  for(int g=0;g<8;g++){
    float v = lacc[g];
    v += __shfl_xor(v,16); v += __shfl_xor(v,32);
    lacc[g] = v;
  }
  if(lane < 16){
    #pragma unroll
    for(int g=0;g<8;g++)
      Lpart[(((size_t)c*NB + b)*NH + g)*NP + i0 + lane] = lacc[g];
  }
}

// ---------------- attn sweep 2 (fallback): full recompute -----------------
__global__ __launch_bounds__(128,2) void attn2_kern(const unsigned short* __restrict__ Qs,
    const unsigned short* __restrict__ Kk, const unsigned short* __restrict__ VA,
    const float* __restrict__ W1, const float* __restrict__ W2,
    const float* __restrict__ Lpart, unsigned short* __restrict__ Opart){
  const int bx = blockIdx.x;
  const int c = bx & 7;
  const int b = (bx>>3) & 1;
  const int it = bx>>4;
  const int tid = threadIdx.x;
  const int iw = tid>>6, lane = tid&63, m = lane&15, q = lane>>4;
  const int i0 = it*32 + iw*16;
  const int cb = c*(NP/JC2);

  __shared__ unsigned short Osh[32*OPITCH];

  float w1[8][8], w2[8][8];
  #pragma unroll
  for(int h=0;h<8;h++)
    #pragma unroll
    for(int g=0;g<8;g++){ w1[h][g]=W1[h*8+g]; w2[h][g]=W2[h*8+g]; }

  const unsigned short* Qb = Qs + (size_t)b*NH*NP*DH;
  const unsigned short* Kb = Kk + (size_t)b*NH*NP*DH;
  const unsigned short* VAb = VA + (size_t)b*(8u*4u*(NP/4)*64u);

  {
    const int qr = lane>>2, qc = (lane&3)*16;
    #pragma unroll
    for(int h=0;h<8;h++){
      const unsigned short* src = Qb + ((size_t)h*NP + i0 + qr)*DH + qc;
      unsigned short* dst = &Osh[(size_t)(iw*16+qr)*OPITCH + h*64 + qc];
      *(u32x4*)dst = *(const u32x4*)src;
      *(u32x4*)(dst+8) = *(const u32x4*)(src+8);
    }
  }

  float rl[8];
  #pragma unroll
  for(int g=0;g<8;g++){
    float v = 0.f;
    #pragma unroll
    for(int cc=0;cc<JC1;cc++)
      v += Lpart[(((size_t)cc*NB + b)*NH + g)*NP + i0 + m];
    rl[g] = 1.0f/v;
  }

  f32x4 Oacc[8][4] = {};
  const unsigned short* QL = &Osh[(size_t)(iw*16+m)*OPITCH];

  for(int jt=0; jt<NT2; jt++){
    const int j0 = cb + jt*16;
    s16x8 K[8][2];
    #pragma unroll
    for(int h=0;h<8;h++){
      const unsigned short* kp = Kb + ((size_t)h*NP + j0 + m)*DH + q*8;
      K[h][0] = *(const s16x8*)(kp);
      K[h][1] = *(const s16x8*)(kp + 32);
    }
    f32x4 s1[8] = {};
    #pragma unroll
    for(int h=0;h<8;h++){
      s16x8 q0 = *(const s16x8*)(QL + h*64 + q*8);
      s16x8 q1 = *(const s16x8*)(QL + h*64 + 32 + q*8);
      f32x4 z = {};
      z = mfma16(K[h][0], q0, z);
      f32x4 Sh = mfma16(K[h][1], q1, z);
      #pragma unroll
      for(int g=0;g<8;g++) s1[g] += Sh*w1[h][g];
    }
    s16x4 Vf[8][4];
    const size_t jq = (size_t)(j0>>2) + q;
    #pragma unroll
    for(int g=0;g<8;g++)
      #pragma unroll
      for(int nt=0;nt<4;nt++)
        Vf[g][nt] = *(const s16x4*)(VAb + ((((size_t)g*4+nt)*(NP/4) + jq)<<6) + (m<<2));
    #pragma unroll
    for(int g=0;g<8;g++){
      #pragma unroll
      for(int r=0;r<4;r++) s1[g][r] = __expf(s1[g][r]);
      s1[g] *= rl[g];
    }
    s16x4 A2[8];
    #pragma unroll
    for(int go=0;go<8;go++){
      f32x4 a = s1[0]*w2[0][go];
      #pragma unroll
      for(int h=1;h<8;h++) a += s1[h]*w2[h][go];
      A2[go] = pack4(a);
    }
    #pragma unroll
    for(int g=0;g<8;g++)
      #pragma unroll
      for(int nt=0;nt<4;nt++)
        Oacc[g][nt] = mfma16k16(Vf[g][nt], A2[g], Oacc[g][nt]);
  }

  #pragma unroll
  for(int g=0;g<8;g++)
    #pragma unroll
    for(int nt=0;nt<4;nt++){
      s16x4 pk = pack4(Oacc[g][nt]);
      *(s16x4*)(&Osh[(size_t)(iw*16 + m)*OPITCH + g*64 + nt*16 + 4*q]) = pk;
    }
  __syncthreads();
  unsigned short* Oc = Opart + (size_t)c*NROWS*DM;
  const size_t R0 = (size_t)b*NP + (size_t)it*32;
  #pragma unroll
  for(int t=0;t<16;t++){
    int idx = t*128 + tid;
    int row = idx>>6, c8 = idx&63;
    u32x4 v = *(const u32x4*)(&Osh[(size_t)row*OPITCH + c8*8]);
    __builtin_nontemporal_store(v, (u32x4*)(Oc + (R0 + row)*DM + c8*8));
  }
}

// ---------------- attn sweep 2 (P-load, go-split, deep-rotated, 16B) ------
// r16/r17 verified: 2-step Pf+Vf pipeline, go-half, plain Pm loads. r18:
// (1) Pm read as 16B g-pairs (matches attn1p's [jt][g/2][lane][8] layout) —
// halves P-path VMEM issues per buffer; (2) Opart epilogue stores PLAIN so
// reduce_kern (immediately after) reads a warm 32 MB buffer.
__global__ __launch_bounds__(128,2) void attn2p_kern(const unsigned short* __restrict__ Pm,
    const unsigned short* __restrict__ VA, const float* __restrict__ W2,
    const float* __restrict__ Lpart, unsigned short* __restrict__ Opart){
  const int bx = blockIdx.x;
  const int go0 = blockIdx.y;            // 0/1 -> output heads go0*4..go0*4+3
  const int c = bx & 7;                  // chunk, pinned to XCD
  const int b = (bx>>3) & 1;
  const int it = bx>>4;                  // 0..63
  const int tid = threadIdx.x;
  const int iw = tid>>6, lane = tid&63, m = lane&15, q = lane>>4;
  const int i0 = it*32 + iw*16;
  const int cb = c*(NP/JC2);

  __shared__ unsigned short Osh[32*SPITCH];   // 32 x 256-col slab epilogue

  float w2[8][4];
  #pragma unroll
  for(int h=0;h<8;h++)
    #pragma unroll
    for(int g=0;g<4;g++) w2[h][g]=W2[h*8 + go0*4 + g];

  const unsigned short* VAb = VA + (size_t)b*(8u*4u*(NP/4)*64u);
  const unsigned short* Pw = Pm + (((size_t)bx*2 + iw)*16)*8*64*4;

  u32x4 PfA[4], PfB[4];
  s16x4 VfA[4][4], VfB[4][4];

  // prologue: load jt=0 fragments (overlaps the rl gather below)
  #pragma unroll
  for(int gp=0;gp<4;gp++)
    PfA[gp] = *(const u32x4*)(Pw + ((size_t)gp*64 + lane)*8);
  {
    const size_t jq0 = (size_t)(cb>>2) + q;
    #pragma unroll
    for(int g=0;g<4;g++){
      const int gh = go0*4 + g;
      #pragma unroll
      for(int nt=0;nt<4;nt++)
        VfA[g][nt] = *(const s16x4*)(VAb + ((((size_t)gh*4+nt)*(NP/4) + jq0)<<6) + (m<<2));
    }
  }

  // 1/l for this wave's 16 columns (i = i0 + lane&15); all 8 input heads
  float rl[8];
  #pragma unroll
  for(int g=0;g<8;g++){
    float v = 0.f;
    #pragma unroll
    for(int cc=0;cc<JC1;cc++)
      v += Lpart[(((size_t)cc*NB + b)*NH + g)*NP + i0 + m];
    rl[g] = 1.0f/v;
  }

  f32x4 Oacc[4][4] = {};

  for(int jt2=0; jt2<NT2; jt2+=2){
    // ---- even step: consume A (jt2), prefetch B (jt2+1, always valid) ----
    {
      f32x4 s1[8];
      #pragma unroll
      for(int gp=0;gp<4;gp++){
        u32x4 u = PfA[gp];
        f32x4 p0, p1;
        p0[0] = __builtin_bit_cast(float, u[0]<<16);
        p0[1] = __builtin_bit_cast(float, u[0] & 0xffff0000u);
        p0[2] = __builtin_bit_cast(float, u[1]<<16);
        p0[3] = __builtin_bit_cast(float, u[1] & 0xffff0000u);
        p1[0] = __builtin_bit_cast(float, u[2]<<16);
        p1[1] = __builtin_bit_cast(float, u[2] & 0xffff0000u);
        p1[2] = __builtin_bit_cast(float, u[3]<<16);
        p1[3] = __builtin_bit_cast(float, u[3] & 0xffff0000u);
        s1[2*gp]   = p0 * rl[2*gp];
        s1[2*gp+1] = p1 * rl[2*gp+1];
      }
      const unsigned short* Pn = Pw + (size_t)(jt2+1)*8*64*4;
      #pragma unroll
      for(int gp=0;gp<4;gp++)
        PfB[gp] = *(const u32x4*)(Pn + ((size_t)gp*64 + lane)*8);
      const size_t jqn = (size_t)((cb + (jt2+1)*16)>>2) + q;
      #pragma unroll
      for(int g=0;g<4;g++){
        const int gh = go0*4 + g;
        #pragma unroll
        for(int nt=0;nt<4;nt++)
          VfB[g][nt] = *(const s16x4*)(VAb + ((((size_t)gh*4+nt)*(NP/4) + jqn)<<6) + (m<<2));
      }
      #pragma unroll
      for(int g=0;g<4;g++){
        f32x4 a = s1[0]*w2[0][g];
        #pragma unroll
        for(int h=1;h<8;h++) a += s1[h]*w2[h][g];
        s16x4 A2 = pack4(a);
        #pragma unroll
        for(int nt=0;nt<4;nt++)
          Oacc[g][nt] = mfma16k16(VfA[g][nt], A2, Oacc[g][nt]);
      }
    }
    // ---- odd step: consume B (jt2+1), prefetch A (jt2+2 if valid) ----
    {
      f32x4 s1[8];
      #pragma unroll
      for(int gp=0;gp<4;gp++){
        u32x4 u = PfB[gp];
        f32x4 p0, p1;
        p0[0] = __builtin_bit_cast(float, u[0]<<16);
        p0[1] = __builtin_bit_cast(float, u[0] & 0xffff0000u);
        p0[2] = __builtin_bit_cast(float, u[1]<<16);
        p0[3] = __builtin_bit_cast(float, u[1] & 0xffff0000u);
        p1[0] = __builtin_bit_cast(float, u[2]<<16);
        p1[1] = __builtin_bit_cast(float, u[2] & 0xffff0000u);
        p1[2] = __builtin_bit_cast(float, u[3]<<16);
        p1[3] = __builtin_bit_cast(float, u[3] & 0xffff0000u);
        s1[2*gp]   = p0 * rl[2*gp];
        s1[2*gp+1] = p1 * rl[2*gp+1];
      }
      if(jt2+2 < NT2){
        const unsigned short* Pn = Pw + (size_t)(jt2+2)*8*64*4;
        #pragma unroll
        for(int gp=0;gp<4;gp++)
          PfA[gp] = *(const u32x4*)(Pn + ((size_t)gp*64 + lane)*8);
        const size_t jqn = (size_t)((cb + (jt2+2)*16)>>2) + q;
        #pragma unroll
        for(int g=0;g<4;g++){
          const int gh = go0*4 + g;
          #pragma unroll
          for(int nt=0;nt<4;nt++)
            VfA[g][nt] = *(const s16x4*)(VAb + ((((size_t)gh*4+nt)*(NP/4) + jqn)<<6) + (m<<2));
        }
      }
      #pragma unroll
      for(int g=0;g<4;g++){
        f32x4 a = s1[0]*w2[0][g];
        #pragma unroll
        for(int h=1;h<8;h++) a += s1[h]*w2[h][g];
        s16x4 A2 = pack4(a);
        #pragma unroll
        for(int nt=0;nt<4;nt++)
          Oacc[g][nt] = mfma16k16(VfB[g][nt], A2, Oacc[g][nt]);
      }
    }
  }

  // epilogue: 32x256 slab via LDS, coalesced PLAIN stores (reduce reads next)
  #pragma unroll
  for(int g=0;g<4;g++)
    #pragma unroll
    for(int nt=0;nt<4;nt++){
      s16x4 pk = pack4(Oacc[g][nt]);
      *(s16x4*)(&Osh[(size_t)(iw*16 + m)*SPITCH + g*64 + nt*16 + 4*q]) = pk;
    }
  __syncthreads();
  unsigned short* Oc = Opart + (size_t)c*NROWS*DM;
  const size_t R0 = (size_t)b*NP + (size_t)it*32;
  const int col0 = go0*256;
  #pragma unroll
  for(int t=0;t<8;t++){
    int idx = t*128 + tid;
    int row = idx>>5, c8 = idx&31;
    u32x4 v = *(const u32x4*)(&Osh[(size_t)row*SPITCH + c8*8]);
    *(u32x4*)(Oc + (R0 + row)*DM + col0 + c8*8) = v;
  }
}

// ---------------- chunk reduction: Of = sum_c Opart_c (bf16, f32 accum) ----
__global__ __launch_bounds__(256) void reduce_kern(const unsigned short* __restrict__ Op,
    unsigned short* __restrict__ Of){
  const size_t i = ((size_t)blockIdx.x*256 + threadIdx.x)*8;
  float acc[8] = {};
  #pragma unroll
  for(int cc=0;cc<JC2;cc++){
    u32x4 v = *(const u32x4*)(Op + (size_t)cc*NROWS*DM + i);
    #pragma unroll
    for(int e=0;e<4;e++){
      unsigned u = v[e];
      acc[2*e]   += __builtin_bit_cast(float, u<<16);
      acc[2*e+1] += __builtin_bit_cast(float, u & 0xffff0000u);
    }
  }
  u32x4 o;
  #pragma unroll
  for(int e=0;e<4;e++)
    o[e] = (unsigned)f2bf(acc[2*e]) | ((unsigned)f2bf(acc[2*e+1])<<16);
  *(u32x4*)(Of + i) = o;
}

// ---------------- output projection: out = Of @ Wproj (single pass) -------
__global__ __launch_bounds__(256) void oproj_kern(const unsigned short* __restrict__ Of,
    const unsigned short* __restrict__ WT, float* __restrict__ out){
  const int nb = blockIdx.y;
  const int R0 = blockIdx.x*64;
  const int tid = threadIdx.x;
  const int w = tid>>6, lane = tid&63, m = lane&15, q = lane>>4;
  const unsigned short* Wp = WT + (size_t)3*DM*DM;
  f32x4 acc[4] = {};
  const unsigned short* brow = Wp + (size_t)(nb*64 + m)*DM + q*8;
  const unsigned short* arow = Of + (size_t)(R0 + w*16 + m)*DM + q*8;
  for(int k=0;k<DM;k+=32){
    s16x8 A = *(const s16x8*)(arow + k);
    #pragma unroll
    for(int nt=0;nt<4;nt++){
      s16x8 B = *(const s16x8*)(brow + (size_t)nt*16*DM + k);
      acc[nt] = mfma16(A, B, acc[nt]);
    }
  }
  #pragma unroll
  for(int nt=0;nt<4;nt++)
    #pragma unroll
    for(int r=0;r<4;r++)
      out[(size_t)(R0 + w*16 + q*4 + r)*DM + nb*64 + nt*16 + m] = acc[nt][r];
}

extern "C" void kernel_launch(void* const* d_in, const int* in_sizes, int n_in,
                              void* d_out, int out_size, void* d_ws, size_t ws_size,
                              hipStream_t stream){
  (void)in_sizes; (void)n_in; (void)out_size;
  const float* x  = (const float*)d_in[0];
  const float* Wq = (const float*)d_in[1];
  const float* Wk = (const float*)d_in[2];
  const float* Wv = (const float*)d_in[3];
  const float* W1 = (const float*)d_in[4];
  const float* W2 = (const float*)d_in[5];
  const float* Wp = (const float*)d_in[6];

  char* ws = (char*)d_ws;
  unsigned short* xb = (unsigned short*)ws;  ws += (size_t)NROWS*DM*2;     // 4 MB
  unsigned short* WT = (unsigned short*)ws;  ws += (size_t)4*DM*DM*2;      // 2 MB
  unsigned short* Qs = (unsigned short*)ws;  ws += (size_t)NB*NH*NP*DH*2;  // 4 MB
  unsigned short* Kk = (unsigned short*)ws;  ws += (size_t)NB*NH*NP*DH*2;  // 4 MB
  unsigned short* VA = (unsigned short*)ws;  ws += (size_t)NB*NH*DH*NP*2;  // 4 MB
  float*          Lp = (float*)ws;           ws += (size_t)JC1*NB*NH*NP*4; // 2 MB
  unsigned short* Op = (unsigned short*)ws;  ws += (size_t)JC2*NROWS*DM*2; // 32 MB
  unsigned short* Pm = (unsigned short*)ws;  // 128 MiB if it fits
  const size_t pm_bytes = (size_t)1024*2*16*8*64*4*2;  // [bx][iw][jt][g/2][lane]x8
  const size_t need = (size_t)((char*)Pm - (char*)d_ws) + pm_bytes;
  unsigned short* Of = xb;  // alias: xb is dead after qkv_kern

  prep_x<<<NROWS*DM/1024, 256, 0, stream>>>(x, xb);
  prep_w<<<dim3(8,8,4), 256, 0, stream>>>(Wq, Wk, Wv, Wp, WT);
  qkv_kern<<<dim3(64,8,3), 256, 0, stream>>>(xb, WT, Qs, Kk, VA);
  if(ws_size >= need){
    attn1p_kern<<<dim3(1024), 128, 0, stream>>>(Qs, Kk, W1, Lp, Pm);
    attn2p_kern<<<dim3(1024,2), 128, 0, stream>>>(Pm, VA, W2, Lp, Op);
  } else {
    attn1_kern<<<dim3(1024), 128, 0, stream>>>(Qs, Kk, W1, Lp);
    attn2_kern<<<dim3(1024), 128, 0, stream>>>(Qs, Kk, VA, W1, W2, Lp, Op);
  }
  reduce_kern<<<dim3(NROWS*DM/2048), 256, 0, stream>>>(Op, Of);
  oproj_kern<<<dim3(64,8), 256, 0, stream>>>(Of, WT, (float*)d_out);
}

// Round 19
// 294.481 us; speedup vs baseline: 1.1905x; 1.0037x over previous
//
#include <hip/hip_runtime.h>
#include <hip/hip_bf16.h>

#define DM 512
#define DH 64
#define NH 8
#define NP 2048
#define NB 2
#define NROWS (NB*NP)
#define JC1 8            // attn1 j-chunks (chunk = 256 j, 16 jt of 16)
#define JC2 8            // attn2 j-chunks (chunk = 256 j, 16 jt of 16)
#define NT1 (NP/JC1/16)  // 16
#define NT2 (NP/JC2/16)  // 16
#define OPITCH 520       // LDS pitch (shorts) for 512-wide tiles
#define SPITCH 264       // LDS pitch (shorts) for 256-wide slab (attn2p epilogue)

typedef short s16x8 __attribute__((ext_vector_type(8)));
typedef short s16x4 __attribute__((ext_vector_type(4)));
typedef float f32x4 __attribute__((ext_vector_type(4)));
typedef unsigned int u32x4 __attribute__((ext_vector_type(4)));
typedef unsigned int u32x2 __attribute__((ext_vector_type(2)));

__device__ __forceinline__ unsigned short f2bf(float f){
  __hip_bfloat16 h = __float2bfloat16(f);
  return __builtin_bit_cast(unsigned short, h);
}

__device__ __forceinline__ f32x4 mfma16(s16x8 a, s16x8 b, f32x4 c){
  return __builtin_amdgcn_mfma_f32_16x16x32_bf16(a, b, c, 0, 0, 0);
}

__device__ __forceinline__ f32x4 mfma16k16(s16x4 a, s16x4 b, f32x4 c){
#if __has_builtin(__builtin_amdgcn_mfma_f32_16x16x16bf16_1k)
  return __builtin_amdgcn_mfma_f32_16x16x16bf16_1k(a, b, c, 0, 0, 0);
#else
  asm volatile("v_mfma_f32_16x16x16_bf16 %0, %1, %2, %0\n\ts_nop 7\n\ts_nop 7"
               : "+v"(c) : "v"(a), "v"(b));
  return c;
#endif
}

__device__ __forceinline__ s16x4 pack4(f32x4 a){
  u32x2 u;
  u.x = (unsigned)f2bf(a[0]) | ((unsigned)f2bf(a[1])<<16);
  u.y = (unsigned)f2bf(a[2]) | ((unsigned)f2bf(a[3])<<16);
  return __builtin_bit_cast(s16x4, u);
}

// ---------------- prep: x fp32 -> bf16 ----------------
__global__ void prep_x(const float* __restrict__ x, unsigned short* __restrict__ xb){
  int i = (blockIdx.x*256 + threadIdx.x)*4;
  float4 v = *(const float4*)(x + i);
  unsigned short s0=f2bf(v.x), s1=f2bf(v.y), s2=f2bf(v.z), s3=f2bf(v.w);
  uint2 u; u.x = (unsigned)s0 | ((unsigned)s1<<16); u.y = (unsigned)s2 | ((unsigned)s3<<16);
  *(uint2*)(xb + i) = u;
}

// ---------------- prep: transpose weights to [n][k] bf16 ----------------
__global__ void prep_w(const float* __restrict__ Wq, const float* __restrict__ Wk,
                       const float* __restrict__ Wv, const float* __restrict__ Wp,
                       unsigned short* __restrict__ WT){
  __shared__ float t[64][65];
  const float* W = (blockIdx.z==0)?Wq:(blockIdx.z==1)?Wk:(blockIdx.z==2)?Wv:Wp;
  const int k0 = blockIdx.x*64, n0 = blockIdx.y*64;
  const int c = threadIdx.x&63, rq = threadIdx.x>>6;
  #pragma unroll
  for(int rr=0;rr<16;rr++){
    int kl = rq*16+rr;
    t[kl][c] = W[(size_t)(k0+kl)*DM + n0 + c];
  }
  __syncthreads();
  unsigned short* o = WT + (size_t)blockIdx.z*DM*DM;
  #pragma unroll
  for(int rr=0;rr<16;rr++){
    int nl = rq*16+rr;
    o[(size_t)(n0+nl)*DM + k0 + c] = f2bf(t[c][nl]);
  }
}

// ---------------- QKV projection GEMM ----------------
// z=0: Qs (scaled 1/8) [b][h][p][d]; z=1: K [b][h][p][d];
// z=2: VA — V^T packed [b][g][p/4][d&15][nt=d>>4][p&3]: the 4 nt-fragments
// of one (g,jq,m) are 16 consecutive shorts -> 16B-pair loads in attn2p.
__global__ __launch_bounds__(256) void qkv_kern(const unsigned short* __restrict__ xb,
    const unsigned short* __restrict__ WT,
    unsigned short* __restrict__ Qs, unsigned short* __restrict__ Kk,
    unsigned short* __restrict__ VA){
  const int z = blockIdx.z, h = blockIdx.y;
  const int R0 = blockIdx.x*64;
  const int tid = threadIdx.x;
  const int w = tid>>6, lane = tid&63, m = lane&15, q = lane>>4;
  const unsigned short* Wz = WT + (size_t)z*DM*DM;
  f32x4 acc[4] = {};
  const unsigned short* arow = xb + (size_t)(R0 + w*16 + m)*DM + q*8;
  const unsigned short* brow = Wz + (size_t)(h*64 + m)*DM + q*8;
  for(int k=0;k<DM;k+=32){
    s16x8 A = *(const s16x8*)(arow + k);
    #pragma unroll
    for(int nt=0;nt<4;nt++){
      s16x8 B = *(const s16x8*)(brow + (size_t)nt*16*DM + k);
      acc[nt] = mfma16(A, B, acc[nt]);
    }
  }
  __shared__ float t[64][65];
  const float scale = (z==0) ? 0.125f : 1.0f;
  #pragma unroll
  for(int nt=0;nt<4;nt++)
    #pragma unroll
    for(int r=0;r<4;r++)
      t[w*16 + q*4 + r][nt*16 + m] = acc[nt][r]*scale;
  __syncthreads();
  const int b = R0>>11, p0 = R0&2047;
  if(z<2){
    unsigned short* outp = (z==0)? Qs : Kk;
    int pl = tid>>2, c0 = (tid&3)*16;
    unsigned short vbuf[16];
    #pragma unroll
    for(int i=0;i<16;i++) vbuf[i]=f2bf(t[pl][c0+i]);
    unsigned short* dst = outp + ((size_t)(b*NH+h)*NP + p0+pl)*DH + c0;
    uint4 u0, u1;
    u0.x=(unsigned)vbuf[0]|((unsigned)vbuf[1]<<16);  u0.y=(unsigned)vbuf[2]|((unsigned)vbuf[3]<<16);
    u0.z=(unsigned)vbuf[4]|((unsigned)vbuf[5]<<16);  u0.w=(unsigned)vbuf[6]|((unsigned)vbuf[7]<<16);
    u1.x=(unsigned)vbuf[8]|((unsigned)vbuf[9]<<16);  u1.y=(unsigned)vbuf[10]|((unsigned)vbuf[11]<<16);
    u1.z=(unsigned)vbuf[12]|((unsigned)vbuf[13]<<16);u1.w=(unsigned)vbuf[14]|((unsigned)vbuf[15]<<16);
    *(uint4*)dst = u0; *(uint4*)(dst+8) = u1;
  } else {
    int d = tid>>2, c0 = (tid&3)*16;
    // new layout: [g=h][jq][m=d&15][nt=d>>4][pp] ; element stride per jq = 256
    unsigned short* vb = VA + (size_t)b*(8u*(NP/4)*256u)
        + (size_t)h*(NP/4)*256 + (size_t)(d&15)*16 + (size_t)(d>>4)*4;
    #pragma unroll
    for(int grp=0; grp<4; grp++){
      int pl = c0 + grp*4;
      unsigned short v4[4];
      #pragma unroll
      for(int tt=0; tt<4; tt++) v4[tt] = f2bf(t[pl+tt][d]);
      uint2 u; u.x = (unsigned)v4[0] | ((unsigned)v4[1]<<16);
      u.y = (unsigned)v4[2] | ((unsigned)v4[3]<<16);
      *(uint2*)(vb + (size_t)((p0 + pl)>>2)*256) = u;
    }
  }
}

// ---------------- attn sweep 1 (fallback): denominators only --------------
// DO NOT peephole the attn inner loops: r1/r2 showed any perturbation of the
// instruction stream tips the 256-reg knife edge into scratch spills.
// NOTE (r11): fusing the two sweeps is mathematically INVALID — the W2 mix
// couples P-head h with V-head go; two sweeps (or P materialization) forced.
__global__ __launch_bounds__(128,2) void attn1_kern(const unsigned short* __restrict__ Qs,
    const unsigned short* __restrict__ Kk, const float* __restrict__ W1,
    float* __restrict__ Lpart){
  const int bx = blockIdx.x;
  const int c = bx & 7;
  const int b = (bx>>3) & 1;
  const int it = bx>>4;                  // 0..63
  const int tid = threadIdx.x;
  const int iw = tid>>6, lane = tid&63, m = lane&15, q = lane>>4;
  const int i0 = it*32 + iw*16;
  const int cb = c*(NP/JC1);

  float w1[8][8];
  #pragma unroll
  for(int h=0;h<8;h++)
    #pragma unroll
    for(int g=0;g<8;g++) w1[h][g]=W1[h*8+g];

  const unsigned short* Qb = Qs + (size_t)b*NH*NP*DH;
  const unsigned short* Kb = Kk + (size_t)b*NH*NP*DH;

  s16x8 Qf[8][2];
  #pragma unroll
  for(int h=0;h<8;h++){
    const unsigned short* qp = Qb + ((size_t)h*NP + i0 + m)*DH + q*8;
    Qf[h][0] = *(const s16x8*)(qp);
    Qf[h][1] = *(const s16x8*)(qp + 32);
  }

  float lacc[8] = {};
  for(int jt=0; jt<NT1; jt++){
    const int j0 = cb + jt*16;
    s16x8 K[8][2];
    #pragma unroll
    for(int h=0;h<8;h++){
      const unsigned short* kp = Kb + ((size_t)h*NP + j0 + m)*DH + q*8;
      K[h][0] = *(const s16x8*)(kp);
      K[h][1] = *(const s16x8*)(kp + 32);
    }
    f32x4 s1[8] = {};
    #pragma unroll
    for(int h=0;h<8;h++){
      f32x4 z = {};
      z = mfma16(K[h][0], Qf[h][0], z);       // A=K (m=j), B=Q (n=i) -> S^T
      f32x4 Sh = mfma16(K[h][1], Qf[h][1], z);
      #pragma unroll
      for(int g=0;g<8;g++) s1[g] += Sh*w1[h][g];
    }
    #pragma unroll
    for(int g=0;g<8;g++)
      #pragma unroll
      for(int r=0;r<4;r++) lacc[g] += __expf(s1[g][r]);
  }
  #pragma unroll
  for(int g=0;g<8;g++){
    float v = lacc[g];
    v += __shfl_xor(v,16); v += __shfl_xor(v,32);
    lacc[g] = v;
  }
  if(lane < 16){
    #pragma unroll
    for(int g=0;g<8;g++)
      Lpart[(((size_t)c*NB + b)*NH + g)*NP + i0 + lane] = lacc[g];
  }
}

// ---------------- attn sweep 1 (P-store, per-h K-rotated, 16B pairs) ------
// r10 structure + r17 plain stores + r18 16B g-pair stores. Bit-identical.
__global__ __launch_bounds__(128,2) void attn1p_kern(const unsigned short* __restrict__ Qs,
    const unsigned short* __restrict__ Kk, const float* __restrict__ W1,
    float* __restrict__ Lpart, unsigned short* __restrict__ Pm){
  const int bx = blockIdx.x;
  const int c = bx & 7;
  const int b = (bx>>3) & 1;
  const int it = bx>>4;                  // 0..63
  const int tid = threadIdx.x;
  const int iw = tid>>6, lane = tid&63, m = lane&15, q = lane>>4;
  const int i0 = it*32 + iw*16;
  const int cb = c*(NP/JC1);

  float w1[8][8];
  #pragma unroll
  for(int h=0;h<8;h++)
    #pragma unroll
    for(int g=0;g<8;g++) w1[h][g]=W1[h*8+g];

  const unsigned short* Qb = Qs + (size_t)b*NH*NP*DH;
  const unsigned short* Kb = Kk + (size_t)b*NH*NP*DH;
  unsigned short* Pw = Pm + (((size_t)bx*2 + iw)*16)*8*64*4;

  s16x8 Qf[8][2];
  #pragma unroll
  for(int h=0;h<8;h++){
    const unsigned short* qp = Qb + ((size_t)h*NP + i0 + m)*DH + q*8;
    Qf[h][0] = *(const s16x8*)(qp);
    Qf[h][1] = *(const s16x8*)(qp + 32);
  }

  // preload K tile for jt=0
  s16x8 K[8][2];
  #pragma unroll
  for(int h=0;h<8;h++){
    const unsigned short* kp = Kb + ((size_t)h*NP + cb + m)*DH + q*8;
    K[h][0] = *(const s16x8*)(kp);
    K[h][1] = *(const s16x8*)(kp + 32);
  }

  float lacc[8] = {};
  for(int jt=0; jt<NT1; jt++){
    const int j1 = cb + (jt+1)*16;
    f32x4 s1[8] = {};
    #pragma unroll
    for(int h=0;h<8;h++){
      f32x4 z = {};
      z = mfma16(K[h][0], Qf[h][0], z);       // A=K (m=j), B=Q (n=i) -> S^T
      f32x4 Sh = mfma16(K[h][1], Qf[h][1], z);
      // K[h] dead now: reload in place with next jt's tile
      if(jt+1 < NT1){
        const unsigned short* kp = Kb + ((size_t)h*NP + j1 + m)*DH + q*8;
        K[h][0] = *(const s16x8*)(kp);
        K[h][1] = *(const s16x8*)(kp + 32);
      }
      #pragma unroll
      for(int g=0;g<8;g++) s1[g] += Sh*w1[h][g];
    }
    unsigned short* Pjt = Pw + (size_t)jt*8*64*4;
    u32x2 pkE = {};
    #pragma unroll
    for(int g=0;g<8;g++){
      f32x4 e;
      #pragma unroll
      for(int r=0;r<4;r++){ e[r] = __expf(s1[g][r]); lacc[g] += e[r]; }
      u32x2 pk = __builtin_bit_cast(u32x2, pack4(e));
      if((g&1)==0){
        pkE = pk;
      } else {
        u32x4 pp; pp[0]=pkE.x; pp[1]=pkE.y; pp[2]=pk.x; pp[3]=pk.y;
        *(u32x4*)(Pjt + (((size_t)(g>>1))*64 + lane)*8) = pp;
      }
    }
  }
  #pragma unroll
  for(int g=0;g<8;g++){
    float v = lacc[g];
    v += __shfl_xor(v,16); v += __shfl_xor(v,32);
    lacc[g] = v;
  }
  if(lane < 16){
    #pragma unroll
    for(int g=0;g<8;g++)
      Lpart[(((size_t)c*NB + b)*NH + g)*NP + i0 + lane] = lacc[g];
  }
}

// ---------------- attn sweep 2 (fallback): full recompute -----------------
__global__ __launch_bounds__(128,2) void attn2_kern(const unsigned short* __restrict__ Qs,
    const unsigned short* __restrict__ Kk, const unsigned short* __restrict__ VA,
    const float* __restrict__ W1, const float* __restrict__ W2,
    const float* __restrict__ Lpart, unsigned short* __restrict__ Opart){
  const int bx = blockIdx.x;
  const int c = bx & 7;
  const int b = (bx>>3) & 1;
  const int it = bx>>4;
  const int tid = threadIdx.x;
  const int iw = tid>>6, lane = tid&63, m = lane&15, q = lane>>4;
  const int i0 = it*32 + iw*16;
  const int cb = c*(NP/JC2);

  __shared__ unsigned short Osh[32*OPITCH];

  float w1[8][8], w2[8][8];
  #pragma unroll
  for(int h=0;h<8;h++)
    #pragma unroll
    for(int g=0;g<8;g++){ w1[h][g]=W1[h*8+g]; w2[h][g]=W2[h*8+g]; }

  const unsigned short* Qb = Qs + (size_t)b*NH*NP*DH;
  const unsigned short* Kb = Kk + (size_t)b*NH*NP*DH;
  const unsigned short* VAb = VA + (size_t)b*(8u*(NP/4)*256u);

  {
    const int qr = lane>>2, qc = (lane&3)*16;
    #pragma unroll
    for(int h=0;h<8;h++){
      const unsigned short* src = Qb + ((size_t)h*NP + i0 + qr)*DH + qc;
      unsigned short* dst = &Osh[(size_t)(iw*16+qr)*OPITCH + h*64 + qc];
      *(u32x4*)dst = *(const u32x4*)src;
      *(u32x4*)(dst+8) = *(const u32x4*)(src+8);
    }
  }

  float rl[8];
  #pragma unroll
  for(int g=0;g<8;g++){
    float v = 0.f;
    #pragma unroll
    for(int cc=0;cc<JC1;cc++)
      v += Lpart[(((size_t)cc*NB + b)*NH + g)*NP + i0 + m];
    rl[g] = 1.0f/v;
  }

  f32x4 Oacc[8][4] = {};
  const unsigned short* QL = &Osh[(size_t)(iw*16+m)*OPITCH];

  for(int jt=0; jt<NT2; jt++){
    const int j0 = cb + jt*16;
    s16x8 K[8][2];
    #pragma unroll
    for(int h=0;h<8;h++){
      const unsigned short* kp = Kb + ((size_t)h*NP + j0 + m)*DH + q*8;
      K[h][0] = *(const s16x8*)(kp);
      K[h][1] = *(const s16x8*)(kp + 32);
    }
    f32x4 s1[8] = {};
    #pragma unroll
    for(int h=0;h<8;h++){
      s16x8 q0 = *(const s16x8*)(QL + h*64 + q*8);
      s16x8 q1 = *(const s16x8*)(QL + h*64 + 32 + q*8);
      f32x4 z = {};
      z = mfma16(K[h][0], q0, z);
      f32x4 Sh = mfma16(K[h][1], q1, z);
      #pragma unroll
      for(int g=0;g<8;g++) s1[g] += Sh*w1[h][g];
    }
    s16x4 Vf[8][4];
    const size_t jq = (size_t)(j0>>2) + q;
    #pragma unroll
    for(int g=0;g<8;g++)
      #pragma unroll
      for(int nt=0;nt<4;nt++)
        Vf[g][nt] = *(const s16x4*)(VAb + (((size_t)g*(NP/4) + jq)<<8) + (m<<4) + nt*4);
    #pragma unroll
    for(int g=0;g<8;g++){
      #pragma unroll
      for(int r=0;r<4;r++) s1[g][r] = __expf(s1[g][r]);
      s1[g] *= rl[g];
    }
    s16x4 A2[8];
    #pragma unroll
    for(int go=0;go<8;go++){
      f32x4 a = s1[0]*w2[0][go];
      #pragma unroll
      for(int h=1;h<8;h++) a += s1[h]*w2[h][go];
      A2[go] = pack4(a);
    }
    #pragma unroll
    for(int g=0;g<8;g++)
      #pragma unroll
      for(int nt=0;nt<4;nt++)
        Oacc[g][nt] = mfma16k16(Vf[g][nt], A2[g], Oacc[g][nt]);
  }

  #pragma unroll
  for(int g=0;g<8;g++)
    #pragma unroll
    for(int nt=0;nt<4;nt++){
      s16x4 pk = pack4(Oacc[g][nt]);
      *(s16x4*)(&Osh[(size_t)(iw*16 + m)*OPITCH + g*64 + nt*16 + 4*q]) = pk;
    }
  __syncthreads();
  unsigned short* Oc = Opart + (size_t)c*NROWS*DM;
  const size_t R0 = (size_t)b*NP + (size_t)it*32;
  #pragma unroll
  for(int t=0;t<16;t++){
    int idx = t*128 + tid;
    int row = idx>>6, c8 = idx&63;
    u32x4 v = *(const u32x4*)(&Osh[(size_t)row*OPITCH + c8*8]);
    __builtin_nontemporal_store(v, (u32x4*)(Oc + (R0 + row)*DM + c8*8));
  }
}

// ---------------- attn sweep 2 (P-load, go-split, deep-rotated, 16B×2) ----
// r18 verified +20us from halving P-path VMEM issues. r19: same lever on
// the V path — VA reordered so the 4 nt-fragments of one (g,jq,m) are 16
// consecutive shorts; two 16B loads replace four 8B loads per (g,jt).
// s16x4 MFMA operands are register-aligned halves (shufflevector, no VALU).
__global__ __launch_bounds__(128,2) void attn2p_kern(const unsigned short* __restrict__ Pm,
    const unsigned short* __restrict__ VA, const float* __restrict__ W2,
    const float* __restrict__ Lpart, unsigned short* __restrict__ Opart){
  const int bx = blockIdx.x;
  const int go0 = blockIdx.y;            // 0/1 -> output heads go0*4..go0*4+3
  const int c = bx & 7;                  // chunk, pinned to XCD
  const int b = (bx>>3) & 1;
  const int it = bx>>4;                  // 0..63
  const int tid = threadIdx.x;
  const int iw = tid>>6, lane = tid&63, m = lane&15, q = lane>>4;
  const int i0 = it*32 + iw*16;
  const int cb = c*(NP/JC2);

  __shared__ unsigned short Osh[32*SPITCH];   // 32 x 256-col slab epilogue

  float w2[8][4];
  #pragma unroll
  for(int h=0;h<8;h++)
    #pragma unroll
    for(int g=0;g<4;g++) w2[h][g]=W2[h*8 + go0*4 + g];

  const unsigned short* VAb = VA + (size_t)b*(8u*(NP/4)*256u);
  const unsigned short* Pw = Pm + (((size_t)bx*2 + iw)*16)*8*64*4;

  u32x4 PfA[4], PfB[4];
  s16x8 VfA[4][2], VfB[4][2];   // [g][half]: half0 = nt0,1 ; half1 = nt2,3

  // prologue: load jt=0 fragments (overlaps the rl gather below)
  #pragma unroll
  for(int gp=0;gp<4;gp++)
    PfA[gp] = *(const u32x4*)(Pw + ((size_t)gp*64 + lane)*8);
  {
    const size_t jq0 = (size_t)(cb>>2) + q;
    #pragma unroll
    for(int g=0;g<4;g++){
      const int gh = go0*4 + g;
      const unsigned short* vb = VAb + (((size_t)gh*(NP/4) + jq0)<<8) + (m<<4);
      VfA[g][0] = *(const s16x8*)(vb);
      VfA[g][1] = *(const s16x8*)(vb + 8);
    }
  }

  // 1/l for this wave's 16 columns (i = i0 + lane&15); all 8 input heads
  float rl[8];
  #pragma unroll
  for(int g=0;g<8;g++){
    float v = 0.f;
    #pragma unroll
    for(int cc=0;cc<JC1;cc++)
      v += Lpart[(((size_t)cc*NB + b)*NH + g)*NP + i0 + m];
    rl[g] = 1.0f/v;
  }

  f32x4 Oacc[4][4] = {};

  for(int jt2=0; jt2<NT2; jt2+=2){
    // ---- even step: consume A (jt2), prefetch B (jt2+1, always valid) ----
    {
      f32x4 s1[8];
      #pragma unroll
      for(int gp=0;gp<4;gp++){
        u32x4 u = PfA[gp];
        f32x4 p0, p1;
        p0[0] = __builtin_bit_cast(float, u[0]<<16);
        p0[1] = __builtin_bit_cast(float, u[0] & 0xffff0000u);
        p0[2] = __builtin_bit_cast(float, u[1]<<16);
        p0[3] = __builtin_bit_cast(float, u[1] & 0xffff0000u);
        p1[0] = __builtin_bit_cast(float, u[2]<<16);
        p1[1] = __builtin_bit_cast(float, u[2] & 0xffff0000u);
        p1[2] = __builtin_bit_cast(float, u[3]<<16);
        p1[3] = __builtin_bit_cast(float, u[3] & 0xffff0000u);
        s1[2*gp]   = p0 * rl[2*gp];
        s1[2*gp+1] = p1 * rl[2*gp+1];
      }
      const unsigned short* Pn = Pw + (size_t)(jt2+1)*8*64*4;
      #pragma unroll
      for(int gp=0;gp<4;gp++)
        PfB[gp] = *(const u32x4*)(Pn + ((size_t)gp*64 + lane)*8);
      const size_t jqn = (size_t)((cb + (jt2+1)*16)>>2) + q;
      #pragma unroll
      for(int g=0;g<4;g++){
        const int gh = go0*4 + g;
        const unsigned short* vb = VAb + (((size_t)gh*(NP/4) + jqn)<<8) + (m<<4);
        VfB[g][0] = *(const s16x8*)(vb);
        VfB[g][1] = *(const s16x8*)(vb + 8);
      }
      #pragma unroll
      for(int g=0;g<4;g++){
        f32x4 a = s1[0]*w2[0][g];
        #pragma unroll
        for(int h=1;h<8;h++) a += s1[h]*w2[h][g];
        s16x4 A2 = pack4(a);
        Oacc[g][0] = mfma16k16(__builtin_shufflevector(VfA[g][0], VfA[g][0], 0,1,2,3), A2, Oacc[g][0]);
        Oacc[g][1] = mfma16k16(__builtin_shufflevector(VfA[g][0], VfA[g][0], 4,5,6,7), A2, Oacc[g][1]);
        Oacc[g][2] = mfma16k16(__builtin_shufflevector(VfA[g][1], VfA[g][1], 0,1,2,3), A2, Oacc[g][2]);
        Oacc[g][3] = mfma16k16(__builtin_shufflevector(VfA[g][1], VfA[g][1], 4,5,6,7), A2, Oacc[g][3]);
      }
    }
    // ---- odd step: consume B (jt2+1), prefetch A (jt2+2 if valid) ----
    {
      f32x4 s1[8];
      #pragma unroll
      for(int gp=0;gp<4;gp++){
        u32x4 u = PfB[gp];
        f32x4 p0, p1;
        p0[0] = __builtin_bit_cast(float, u[0]<<16);
        p0[1] = __builtin_bit_cast(float, u[0] & 0xffff0000u);
        p0[2] = __builtin_bit_cast(float, u[1]<<16);
        p0[3] = __builtin_bit_cast(float, u[1] & 0xffff0000u);
        p1[0] = __builtin_bit_cast(float, u[2]<<16);
        p1[1] = __builtin_bit_cast(float, u[2] & 0xffff0000u);
        p1[2] = __builtin_bit_cast(float, u[3]<<16);
        p1[3] = __builtin_bit_cast(float, u[3] & 0xffff0000u);
        s1[2*gp]   = p0 * rl[2*gp];
        s1[2*gp+1] = p1 * rl[2*gp+1];
      }
      if(jt2+2 < NT2){
        const unsigned short* Pn = Pw + (size_t)(jt2+2)*8*64*4;
        #pragma unroll
        for(int gp=0;gp<4;gp++)
          PfA[gp] = *(const u32x4*)(Pn + ((size_t)gp*64 + lane)*8);
        const size_t jqn = (size_t)((cb + (jt2+2)*16)>>2) + q;
        #pragma unroll
        for(int g=0;g<4;g++){
          const int gh = go0*4 + g;
          const unsigned short* vb = VAb + (((size_t)gh*(NP/4) + jqn)<<8) + (m<<4);
          VfA[g][0] = *(const s16x8*)(vb);
          VfA[g][1] = *(const s16x8*)(vb + 8);
        }
      }
      #pragma unroll
      for(int g=0;g<4;g++){
        f32x4 a = s1[0]*w2[0][g];
        #pragma unroll
        for(int h=1;h<8;h++) a += s1[h]*w2[h][g];
        s16x4 A2 = pack4(a);
        Oacc[g][0] = mfma16k16(__builtin_shufflevector(VfB[g][0], VfB[g][0], 0,1,2,3), A2, Oacc[g][0]);
        Oacc[g][1] = mfma16k16(__builtin_shufflevector(VfB[g][0], VfB[g][0], 4,5,6,7), A2, Oacc[g][1]);
        Oacc[g][2] = mfma16k16(__builtin_shufflevector(VfB[g][1], VfB[g][1], 0,1,2,3), A2, Oacc[g][2]);
        Oacc[g][3] = mfma16k16(__builtin_shufflevector(VfB[g][1], VfB[g][1], 4,5,6,7), A2, Oacc[g][3]);
      }
    }
  }

  // epilogue: 32x256 slab via LDS, coalesced PLAIN stores (reduce reads next)
  #pragma unroll
  for(int g=0;g<4;g++)
    #pragma unroll
    for(int nt=0;nt<4;nt++){
      s16x4 pk = pack4(Oacc[g][nt]);
      *(s16x4*)(&Osh[(size_t)(iw*16 + m)*SPITCH + g*64 + nt*16 + 4*q]) = pk;
    }
  __syncthreads();
  unsigned short* Oc = Opart + (size_t)c*NROWS*DM;
  const size_t R0 = (size_t)b*NP + (size_t)it*32;
  const int col0 = go0*256;
  #pragma unroll
  for(int t=0;t<8;t++){
    int idx = t*128 + tid;
    int row = idx>>5, c8 = idx&31;
    u32x4 v = *(const u32x4*)(&Osh[(size_t)row*SPITCH + c8*8]);
    *(u32x4*)(Oc + (R0 + row)*DM + col0 + c8*8) = v;
  }
}

// ---------------- chunk reduction: Of = sum_c Opart_c (bf16, f32 accum) ----
__global__ __launch_bounds__(256) void reduce_kern(const unsigned short* __restrict__ Op,
    unsigned short* __restrict__ Of){
  const size_t i = ((size_t)blockIdx.x*256 + threadIdx.x)*8;
  float acc[8] = {};
  #pragma unroll
  for(int cc=0;cc<JC2;cc++){
    u32x4 v = *(const u32x4*)(Op + (size_t)cc*NROWS*DM + i);
    #pragma unroll
    for(int e=0;e<4;e++){
      unsigned u = v[e];
      acc[2*e]   += __builtin_bit_cast(float, u<<16);
      acc[2*e+1] += __builtin_bit_cast(float, u & 0xffff0000u);
    }
  }
  u32x4 o;
  #pragma unroll
  for(int e=0;e<4;e++)
    o[e] = (unsigned)f2bf(acc[2*e]) | ((unsigned)f2bf(acc[2*e+1])<<16);
  *(u32x4*)(Of + i) = o;
}

// ---------------- output projection: out = Of @ Wproj (single pass) -------
__global__ __launch_bounds__(256) void oproj_kern(const unsigned short* __restrict__ Of,
    const unsigned short* __restrict__ WT, float* __restrict__ out){
  const int nb = blockIdx.y;
  const int R0 = blockIdx.x*64;
  const int tid = threadIdx.x;
  const int w = tid>>6, lane = tid&63, m = lane&15, q = lane>>4;
  const unsigned short* Wp = WT + (size_t)3*DM*DM;
  f32x4 acc[4] = {};
  const unsigned short* brow = Wp + (size_t)(nb*64 + m)*DM + q*8;
  const unsigned short* arow = Of + (size_t)(R0 + w*16 + m)*DM + q*8;
  for(int k=0;k<DM;k+=32){
    s16x8 A = *(const s16x8*)(arow + k);
    #pragma unroll
    for(int nt=0;nt<4;nt++){
      s16x8 B = *(const s16x8*)(brow + (size_t)nt*16*DM + k);
      acc[nt] = mfma16(A, B, acc[nt]);
    }
  }
  #pragma unroll
  for(int nt=0;nt<4;nt++)
    #pragma unroll
    for(int r=0;r<4;r++)
      out[(size_t)(R0 + w*16 + q*4 + r)*DM + nb*64 + nt*16 + m] = acc[nt][r];
}

extern "C" void kernel_launch(void* const* d_in, const int* in_sizes, int n_in,
                              void* d_out, int out_size, void* d_ws, size_t ws_size,
                              hipStream_t stream){
  (void)in_sizes; (void)n_in; (void)out_size;
  const float* x  = (const float*)d_in[0];
  const float* Wq = (const float*)d_in[1];
  const float* Wk = (const float*)d_in[2];
  const float* Wv = (const float*)d_in[3];
  const float* W1 = (const float*)d_in[4];
  const float* W2 = (const float*)d_in[5];
  const float* Wp = (const float*)d_in[6];

  char* ws = (char*)d_ws;
  unsigned short* xb = (unsigned short*)ws;  ws += (size_t)NROWS*DM*2;     // 4 MB
  unsigned short* WT = (unsigned short*)ws;  ws += (size_t)4*DM*DM*2;      // 2 MB
  unsigned short* Qs = (unsigned short*)ws;  ws += (size_t)NB*NH*NP*DH*2;  // 4 MB
  unsigned short* Kk = (unsigned short*)ws;  ws += (size_t)NB*NH*NP*DH*2;  // 4 MB
  unsigned short* VA = (unsigned short*)ws;  ws += (size_t)NB*NH*DH*NP*2;  // 4 MB
  float*          Lp = (float*)ws;           ws += (size_t)JC1*NB*NH*NP*4; // 2 MB
  unsigned short* Op = (unsigned short*)ws;  ws += (size_t)JC2*NROWS*DM*2; // 32 MB
  unsigned short* Pm = (unsigned short*)ws;  // 128 MiB if it fits
  const size_t pm_bytes = (size_t)1024*2*16*8*64*4*2;  // [bx][iw][jt][g/2][lane]x8
  const size_t need = (size_t)((char*)Pm - (char*)d_ws) + pm_bytes;
  unsigned short* Of = xb;  // alias: xb is dead after qkv_kern

  prep_x<<<NROWS*DM/1024, 256, 0, stream>>>(x, xb);
  prep_w<<<dim3(8,8,4), 256, 0, stream>>>(Wq, Wk, Wv, Wp, WT);
  qkv_kern<<<dim3(64,8,3), 256, 0, stream>>>(xb, WT, Qs, Kk, VA);
  if(ws_size >= need){
    attn1p_kern<<<dim3(1024), 128, 0, stream>>>(Qs, Kk, W1, Lp, Pm);
    attn2p_kern<<<dim3(1024,2), 128, 0, stream>>>(Pm, VA, W2, Lp, Op);
  } else {
    attn1_kern<<<dim3(1024), 128, 0, stream>>>(Qs, Kk, W1, Lp);
    attn2_kern<<<dim3(1024), 128, 0, stream>>>(Qs, Kk, VA, W1, W2, Lp, Op);
  }
  reduce_kern<<<dim3(NROWS*DM/2048), 256, 0, stream>>>(Op, Of);
  oproj_kern<<<dim3(64,8), 256, 0, stream>>>(Of, WT, (float*)d_out);
}

// Round 20
// 294.427 us; speedup vs baseline: 1.1907x; 1.0002x over previous
//
#include <hip/hip_runtime.h>
#include <hip/hip_bf16.h>

#define DM 512
#define DH 64
#define NH 8
#define NP 2048
#define NB 2
#define NROWS (NB*NP)
#define JC1 8            // attn1 j-chunks (chunk = 256 j, 16 jt of 16)
#define JC2 8            // attn2 j-chunks (chunk = 256 j, 16 jt of 16)
#define NT1 (NP/JC1/16)  // 16
#define NT2 (NP/JC2/16)  // 16
#define OPITCH 520       // LDS pitch (shorts) for 512-wide tiles
#define SPITCH 264       // LDS pitch (shorts) for 256-wide slab (attn2p epilogue)

typedef short s16x8 __attribute__((ext_vector_type(8)));
typedef short s16x4 __attribute__((ext_vector_type(4)));
typedef float f32x4 __attribute__((ext_vector_type(4)));
typedef unsigned int u32x4 __attribute__((ext_vector_type(4)));
typedef unsigned int u32x2 __attribute__((ext_vector_type(2)));

__device__ __forceinline__ unsigned short f2bf(float f){
  __hip_bfloat16 h = __float2bfloat16(f);
  return __builtin_bit_cast(unsigned short, h);
}

__device__ __forceinline__ f32x4 mfma16(s16x8 a, s16x8 b, f32x4 c){
  return __builtin_amdgcn_mfma_f32_16x16x32_bf16(a, b, c, 0, 0, 0);
}

__device__ __forceinline__ f32x4 mfma16k16(s16x4 a, s16x4 b, f32x4 c){
#if __has_builtin(__builtin_amdgcn_mfma_f32_16x16x16bf16_1k)
  return __builtin_amdgcn_mfma_f32_16x16x16bf16_1k(a, b, c, 0, 0, 0);
#else
  asm volatile("v_mfma_f32_16x16x16_bf16 %0, %1, %2, %0\n\ts_nop 7\n\ts_nop 7"
               : "+v"(c) : "v"(a), "v"(b));
  return c;
#endif
}

__device__ __forceinline__ s16x4 pack4(f32x4 a){
  u32x2 u;
  u.x = (unsigned)f2bf(a[0]) | ((unsigned)f2bf(a[1])<<16);
  u.y = (unsigned)f2bf(a[2]) | ((unsigned)f2bf(a[3])<<16);
  return __builtin_bit_cast(s16x4, u);
}

// ---------------- prep: x fp32 -> bf16 ----------------
__global__ void prep_x(const float* __restrict__ x, unsigned short* __restrict__ xb){
  int i = (blockIdx.x*256 + threadIdx.x)*4;
  float4 v = *(const float4*)(x + i);
  unsigned short s0=f2bf(v.x), s1=f2bf(v.y), s2=f2bf(v.z), s3=f2bf(v.w);
  uint2 u; u.x = (unsigned)s0 | ((unsigned)s1<<16); u.y = (unsigned)s2 | ((unsigned)s3<<16);
  *(uint2*)(xb + i) = u;
}

// ---------------- prep: transpose weights to [n][k] bf16 ----------------
__global__ void prep_w(const float* __restrict__ Wq, const float* __restrict__ Wk,
                       const float* __restrict__ Wv, const float* __restrict__ Wp,
                       unsigned short* __restrict__ WT){
  __shared__ float t[64][65];
  const float* W = (blockIdx.z==0)?Wq:(blockIdx.z==1)?Wk:(blockIdx.z==2)?Wv:Wp;
  const int k0 = blockIdx.x*64, n0 = blockIdx.y*64;
  const int c = threadIdx.x&63, rq = threadIdx.x>>6;
  #pragma unroll
  for(int rr=0;rr<16;rr++){
    int kl = rq*16+rr;
    t[kl][c] = W[(size_t)(k0+kl)*DM + n0 + c];
  }
  __syncthreads();
  unsigned short* o = WT + (size_t)blockIdx.z*DM*DM;
  #pragma unroll
  for(int rr=0;rr<16;rr++){
    int nl = rq*16+rr;
    o[(size_t)(n0+nl)*DM + k0 + c] = f2bf(t[c][nl]);
  }
}

// ---------------- QKV projection GEMM ----------------
// z=0: Qs (scaled 1/8) [b][h][p][d]; z=1: K [b][h][p][d];
// z=2: VA — V^T packed [b][g][p/4][d&15][nt=d>>4][p&3]: the 4 nt-fragments
// of one (g,jq,m) are 16 consecutive shorts. r20: epilogue remapped so each
// thread owns one full (g,jq,m) group -> two coalesced 16B stores replace
// four scattered 8B stores. Bit-identical.
__global__ __launch_bounds__(256) void qkv_kern(const unsigned short* __restrict__ xb,
    const unsigned short* __restrict__ WT,
    unsigned short* __restrict__ Qs, unsigned short* __restrict__ Kk,
    unsigned short* __restrict__ VA){
  const int z = blockIdx.z, h = blockIdx.y;
  const int R0 = blockIdx.x*64;
  const int tid = threadIdx.x;
  const int w = tid>>6, lane = tid&63, m = lane&15, q = lane>>4;
  const unsigned short* Wz = WT + (size_t)z*DM*DM;
  f32x4 acc[4] = {};
  const unsigned short* arow = xb + (size_t)(R0 + w*16 + m)*DM + q*8;
  const unsigned short* brow = Wz + (size_t)(h*64 + m)*DM + q*8;
  for(int k=0;k<DM;k+=32){
    s16x8 A = *(const s16x8*)(arow + k);
    #pragma unroll
    for(int nt=0;nt<4;nt++){
      s16x8 B = *(const s16x8*)(brow + (size_t)nt*16*DM + k);
      acc[nt] = mfma16(A, B, acc[nt]);
    }
  }
  __shared__ float t[64][65];
  const float scale = (z==0) ? 0.125f : 1.0f;
  #pragma unroll
  for(int nt=0;nt<4;nt++)
    #pragma unroll
    for(int r=0;r<4;r++)
      t[w*16 + q*4 + r][nt*16 + m] = acc[nt][r]*scale;
  __syncthreads();
  const int b = R0>>11, p0 = R0&2047;
  if(z<2){
    unsigned short* outp = (z==0)? Qs : Kk;
    int pl = tid>>2, c0 = (tid&3)*16;
    unsigned short vbuf[16];
    #pragma unroll
    for(int i=0;i<16;i++) vbuf[i]=f2bf(t[pl][c0+i]);
    unsigned short* dst = outp + ((size_t)(b*NH+h)*NP + p0+pl)*DH + c0;
    uint4 u0, u1;
    u0.x=(unsigned)vbuf[0]|((unsigned)vbuf[1]<<16);  u0.y=(unsigned)vbuf[2]|((unsigned)vbuf[3]<<16);
    u0.z=(unsigned)vbuf[4]|((unsigned)vbuf[5]<<16);  u0.w=(unsigned)vbuf[6]|((unsigned)vbuf[7]<<16);
    u1.x=(unsigned)vbuf[8]|((unsigned)vbuf[9]<<16);  u1.y=(unsigned)vbuf[10]|((unsigned)vbuf[11]<<16);
    u1.z=(unsigned)vbuf[12]|((unsigned)vbuf[13]<<16);u1.w=(unsigned)vbuf[14]|((unsigned)vbuf[15]<<16);
    *(uint4*)dst = u0; *(uint4*)(dst+8) = u1;
  } else {
    // r20: thread owns one (jq,m) group: all nt(4) x pp(4) = 16 consecutive shorts
    const int jql = tid>>4, mm = tid&15;
    unsigned short vbuf[16];
    #pragma unroll
    for(int nt=0;nt<4;nt++)
      #pragma unroll
      for(int pp=0;pp<4;pp++)
        vbuf[nt*4+pp] = f2bf(t[jql*4+pp][mm + nt*16]);
    unsigned short* vb = VA + (size_t)b*(8u*(NP/4)*256u)
        + (size_t)h*(NP/4)*256 + ((size_t)(p0>>2)+jql)*256 + mm*16;
    u32x4 u0, u1;
    #pragma unroll
    for(int k=0;k<4;k++){
      u0[k] = (unsigned)vbuf[2*k]   | ((unsigned)vbuf[2*k+1]<<16);
      u1[k] = (unsigned)vbuf[8+2*k] | ((unsigned)vbuf[8+2*k+1]<<16);
    }
    *(u32x4*)vb = u0;
    *(u32x4*)(vb+8) = u1;
  }
}

// ---------------- attn sweep 1 (fallback): denominators only --------------
// DO NOT peephole the attn inner loops: r1/r2 showed any perturbation of the
// instruction stream tips the 256-reg knife edge into scratch spills.
// NOTE (r11): fusing the two sweeps is mathematically INVALID — the W2 mix
// couples P-head h with V-head go; two sweeps (or P materialization) forced.
__global__ __launch_bounds__(128,2) void attn1_kern(const unsigned short* __restrict__ Qs,
    const unsigned short* __restrict__ Kk, const float* __restrict__ W1,
    float* __restrict__ Lpart){
  const int bx = blockIdx.x;
  const int c = bx & 7;
  const int b = (bx>>3) & 1;
  const int it = bx>>4;                  // 0..63
  const int tid = threadIdx.x;
  const int iw = tid>>6, lane = tid&63, m = lane&15, q = lane>>4;
  const int i0 = it*32 + iw*16;
  const int cb = c*(NP/JC1);

  float w1[8][8];
  #pragma unroll
  for(int h=0;h<8;h++)
    #pragma unroll
    for(int g=0;g<8;g++) w1[h][g]=W1[h*8+g];

  const unsigned short* Qb = Qs + (size_t)b*NH*NP*DH;
  const unsigned short* Kb = Kk + (size_t)b*NH*NP*DH;

  s16x8 Qf[8][2];
  #pragma unroll
  for(int h=0;h<8;h++){
    const unsigned short* qp = Qb + ((size_t)h*NP + i0 + m)*DH + q*8;
    Qf[h][0] = *(const s16x8*)(qp);
    Qf[h][1] = *(const s16x8*)(qp + 32);
  }

  float lacc[8] = {};
  for(int jt=0; jt<NT1; jt++){
    const int j0 = cb + jt*16;
    s16x8 K[8][2];
    #pragma unroll
    for(int h=0;h<8;h++){
      const unsigned short* kp = Kb + ((size_t)h*NP + j0 + m)*DH + q*8;
      K[h][0] = *(const s16x8*)(kp);
      K[h][1] = *(const s16x8*)(kp + 32);
    }
    f32x4 s1[8] = {};
    #pragma unroll
    for(int h=0;h<8;h++){
      f32x4 z = {};
      z = mfma16(K[h][0], Qf[h][0], z);       // A=K (m=j), B=Q (n=i) -> S^T
      f32x4 Sh = mfma16(K[h][1], Qf[h][1], z);
      #pragma unroll
      for(int g=0;g<8;g++) s1[g] += Sh*w1[h][g];
    }
    #pragma unroll
    for(int g=0;g<8;g++)
      #pragma unroll
      for(int r=0;r<4;r++) lacc[g] += __expf(s1[g][r]);
  }
  #pragma unroll
  for(int g=0;g<8;g++){
    float v = lacc[g];
    v += __shfl_xor(v,16); v += __shfl_xor(v,32);
    lacc[g] = v;
  }
  if(lane < 16){
    #pragma unroll
    for(int g=0;g<8;g++)
      Lpart[(((size_t)c*NB + b)*NH + g)*NP + i0 + lane] = lacc[g];
  }
}

// ---------------- attn sweep 1 (P-store, per-h K-rotated, 16B pairs) ------
// r10 structure + r17 plain stores + r18 16B g-pair stores. Bit-identical.
__global__ __launch_bounds__(128,2) void attn1p_kern(const unsigned short* __restrict__ Qs,
    const unsigned short* __restrict__ Kk, const float* __restrict__ W1,
    float* __restrict__ Lpart, unsigned short* __restrict__ Pm){
  const int bx = blockIdx.x;
  const int c = bx & 7;
  const int b = (bx>>3) & 1;
  const int it = bx>>4;                  // 0..63
  const int tid = threadIdx.x;
  const int iw = tid>>6, lane = tid&63, m = lane&15, q = lane>>4;
  const int i0 = it*32 + iw*16;
  const int cb = c*(NP/JC1);

  float w1[8][8];
  #pragma unroll
  for(int h=0;h<8;h++)
    #pragma unroll
    for(int g=0;g<8;g++) w1[h][g]=W1[h*8+g];

  const unsigned short* Qb = Qs + (size_t)b*NH*NP*DH;
  const unsigned short* Kb = Kk + (size_t)b*NH*NP*DH;
  unsigned short* Pw = Pm + (((size_t)bx*2 + iw)*16)*8*64*4;

  s16x8 Qf[8][2];
  #pragma unroll
  for(int h=0;h<8;h++){
    const unsigned short* qp = Qb + ((size_t)h*NP + i0 + m)*DH + q*8;
    Qf[h][0] = *(const s16x8*)(qp);
    Qf[h][1] = *(const s16x8*)(qp + 32);
  }

  // preload K tile for jt=0
  s16x8 K[8][2];
  #pragma unroll
  for(int h=0;h<8;h++){
    const unsigned short* kp = Kb + ((size_t)h*NP + cb + m)*DH + q*8;
    K[h][0] = *(const s16x8*)(kp);
    K[h][1] = *(const s16x8*)(kp + 32);
  }

  float lacc[8] = {};
  for(int jt=0; jt<NT1; jt++){
    const int j1 = cb + (jt+1)*16;
    f32x4 s1[8] = {};
    #pragma unroll
    for(int h=0;h<8;h++){
      f32x4 z = {};
      z = mfma16(K[h][0], Qf[h][0], z);       // A=K (m=j), B=Q (n=i) -> S^T
      f32x4 Sh = mfma16(K[h][1], Qf[h][1], z);
      // K[h] dead now: reload in place with next jt's tile
      if(jt+1 < NT1){
        const unsigned short* kp = Kb + ((size_t)h*NP + j1 + m)*DH + q*8;
        K[h][0] = *(const s16x8*)(kp);
        K[h][1] = *(const s16x8*)(kp + 32);
      }
      #pragma unroll
      for(int g=0;g<8;g++) s1[g] += Sh*w1[h][g];
    }
    unsigned short* Pjt = Pw + (size_t)jt*8*64*4;
    u32x2 pkE = {};
    #pragma unroll
    for(int g=0;g<8;g++){
      f32x4 e;
      #pragma unroll
      for(int r=0;r<4;r++){ e[r] = __expf(s1[g][r]); lacc[g] += e[r]; }
      u32x2 pk = __builtin_bit_cast(u32x2, pack4(e));
      if((g&1)==0){
        pkE = pk;
      } else {
        u32x4 pp; pp[0]=pkE.x; pp[1]=pkE.y; pp[2]=pk.x; pp[3]=pk.y;
        *(u32x4*)(Pjt + (((size_t)(g>>1))*64 + lane)*8) = pp;
      }
    }
  }
  #pragma unroll
  for(int g=0;g<8;g++){
    float v = lacc[g];
    v += __shfl_xor(v,16); v += __shfl_xor(v,32);
    lacc[g] = v;
  }
  if(lane < 16){
    #pragma unroll
    for(int g=0;g<8;g++)
      Lpart[(((size_t)c*NB + b)*NH + g)*NP + i0 + lane] = lacc[g];
  }
}

// ---------------- attn sweep 2 (fallback): full recompute -----------------
__global__ __launch_bounds__(128,2) void attn2_kern(const unsigned short* __restrict__ Qs,
    const unsigned short* __restrict__ Kk, const unsigned short* __restrict__ VA,
    const float* __restrict__ W1, const float* __restrict__ W2,
    const float* __restrict__ Lpart, unsigned short* __restrict__ Opart){
  const int bx = blockIdx.x;
  const int c = bx & 7;
  const int b = (bx>>3) & 1;
  const int it = bx>>4;
  const int tid = threadIdx.x;
  const int iw = tid>>6, lane = tid&63, m = lane&15, q = lane>>4;
  const int i0 = it*32 + iw*16;
  const int cb = c*(NP/JC2);

  __shared__ unsigned short Osh[32*OPITCH];

  float w1[8][8], w2[8][8];
  #pragma unroll
  for(int h=0;h<8;h++)
    #pragma unroll
    for(int g=0;g<8;g++){ w1[h][g]=W1[h*8+g]; w2[h][g]=W2[h*8+g]; }

  const unsigned short* Qb = Qs + (size_t)b*NH*NP*DH;
  const unsigned short* Kb = Kk + (size_t)b*NH*NP*DH;
  const unsigned short* VAb = VA + (size_t)b*(8u*(NP/4)*256u);

  {
    const int qr = lane>>2, qc = (lane&3)*16;
    #pragma unroll
    for(int h=0;h<8;h++){
      const unsigned short* src = Qb + ((size_t)h*NP + i0 + qr)*DH + qc;
      unsigned short* dst = &Osh[(size_t)(iw*16+qr)*OPITCH + h*64 + qc];
      *(u32x4*)dst = *(const u32x4*)src;
      *(u32x4*)(dst+8) = *(const u32x4*)(src+8);
    }
  }

  float rl[8];
  #pragma unroll
  for(int g=0;g<8;g++){
    float v = 0.f;
    #pragma unroll
    for(int cc=0;cc<JC1;cc++)
      v += Lpart[(((size_t)cc*NB + b)*NH + g)*NP + i0 + m];
    rl[g] = 1.0f/v;
  }

  f32x4 Oacc[8][4] = {};
  const unsigned short* QL = &Osh[(size_t)(iw*16+m)*OPITCH];

  for(int jt=0; jt<NT2; jt++){
    const int j0 = cb + jt*16;
    s16x8 K[8][2];
    #pragma unroll
    for(int h=0;h<8;h++){
      const unsigned short* kp = Kb + ((size_t)h*NP + j0 + m)*DH + q*8;
      K[h][0] = *(const s16x8*)(kp);
      K[h][1] = *(const s16x8*)(kp + 32);
    }
    f32x4 s1[8] = {};
    #pragma unroll
    for(int h=0;h<8;h++){
      s16x8 q0 = *(const s16x8*)(QL + h*64 + q*8);
      s16x8 q1 = *(const s16x8*)(QL + h*64 + 32 + q*8);
      f32x4 z = {};
      z = mfma16(K[h][0], q0, z);
      f32x4 Sh = mfma16(K[h][1], q1, z);
      #pragma unroll
      for(int g=0;g<8;g++) s1[g] += Sh*w1[h][g];
    }
    s16x4 Vf[8][4];
    const size_t jq = (size_t)(j0>>2) + q;
    #pragma unroll
    for(int g=0;g<8;g++)
      #pragma unroll
      for(int nt=0;nt<4;nt++)
        Vf[g][nt] = *(const s16x4*)(VAb + (((size_t)g*(NP/4) + jq)<<8) + (m<<4) + nt*4);
    #pragma unroll
    for(int g=0;g<8;g++){
      #pragma unroll
      for(int r=0;r<4;r++) s1[g][r] = __expf(s1[g][r]);
      s1[g] *= rl[g];
    }
    s16x4 A2[8];
    #pragma unroll
    for(int go=0;go<8;go++){
      f32x4 a = s1[0]*w2[0][go];
      #pragma unroll
      for(int h=1;h<8;h++) a += s1[h]*w2[h][go];
      A2[go] = pack4(a);
    }
    #pragma unroll
    for(int g=0;g<8;g++)
      #pragma unroll
      for(int nt=0;nt<4;nt++)
        Oacc[g][nt] = mfma16k16(Vf[g][nt], A2[g], Oacc[g][nt]);
  }

  #pragma unroll
  for(int g=0;g<8;g++)
    #pragma unroll
    for(int nt=0;nt<4;nt++){
      s16x4 pk = pack4(Oacc[g][nt]);
      *(s16x4*)(&Osh[(size_t)(iw*16 + m)*OPITCH + g*64 + nt*16 + 4*q]) = pk;
    }
  __syncthreads();
  unsigned short* Oc = Opart + (size_t)c*NROWS*DM;
  const size_t R0 = (size_t)b*NP + (size_t)it*32;
  #pragma unroll
  for(int t=0;t<16;t++){
    int idx = t*128 + tid;
    int row = idx>>6, c8 = idx&63;
    u32x4 v = *(const u32x4*)(&Osh[(size_t)row*OPITCH + c8*8]);
    __builtin_nontemporal_store(v, (u32x4*)(Oc + (R0 + row)*DM + c8*8));
  }
}

// ---------------- attn sweep 2 (P-load, go-split, deep-rotated, 16B×2) ----
// r18 +20us (P 16B pairs); r19 +4us (V 16B pairs). Near its latency floor
// at 2 waves/SIMD: VALUBusy 38%, MfmaUtil 8.6%, HBM 28%.
__global__ __launch_bounds__(128,2) void attn2p_kern(const unsigned short* __restrict__ Pm,
    const unsigned short* __restrict__ VA, const float* __restrict__ W2,
    const float* __restrict__ Lpart, unsigned short* __restrict__ Opart){
  const int bx = blockIdx.x;
  const int go0 = blockIdx.y;            // 0/1 -> output heads go0*4..go0*4+3
  const int c = bx & 7;                  // chunk, pinned to XCD
  const int b = (bx>>3) & 1;
  const int it = bx>>4;                  // 0..63
  const int tid = threadIdx.x;
  const int iw = tid>>6, lane = tid&63, m = lane&15, q = lane>>4;
  const int i0 = it*32 + iw*16;
  const int cb = c*(NP/JC2);

  __shared__ unsigned short Osh[32*SPITCH];   // 32 x 256-col slab epilogue

  float w2[8][4];
  #pragma unroll
  for(int h=0;h<8;h++)
    #pragma unroll
    for(int g=0;g<4;g++) w2[h][g]=W2[h*8 + go0*4 + g];

  const unsigned short* VAb = VA + (size_t)b*(8u*(NP/4)*256u);
  const unsigned short* Pw = Pm + (((size_t)bx*2 + iw)*16)*8*64*4;

  u32x4 PfA[4], PfB[4];
  s16x8 VfA[4][2], VfB[4][2];   // [g][half]: half0 = nt0,1 ; half1 = nt2,3

  // prologue: load jt=0 fragments (overlaps the rl gather below)
  #pragma unroll
  for(int gp=0;gp<4;gp++)
    PfA[gp] = *(const u32x4*)(Pw + ((size_t)gp*64 + lane)*8);
  {
    const size_t jq0 = (size_t)(cb>>2) + q;
    #pragma unroll
    for(int g=0;g<4;g++){
      const int gh = go0*4 + g;
      const unsigned short* vb = VAb + (((size_t)gh*(NP/4) + jq0)<<8) + (m<<4);
      VfA[g][0] = *(const s16x8*)(vb);
      VfA[g][1] = *(const s16x8*)(vb + 8);
    }
  }

  // 1/l for this wave's 16 columns (i = i0 + lane&15); all 8 input heads
  float rl[8];
  #pragma unroll
  for(int g=0;g<8;g++){
    float v = 0.f;
    #pragma unroll
    for(int cc=0;cc<JC1;cc++)
      v += Lpart[(((size_t)cc*NB + b)*NH + g)*NP + i0 + m];
    rl[g] = 1.0f/v;
  }

  f32x4 Oacc[4][4] = {};

  for(int jt2=0; jt2<NT2; jt2+=2){
    // ---- even step: consume A (jt2), prefetch B (jt2+1, always valid) ----
    {
      f32x4 s1[8];
      #pragma unroll
      for(int gp=0;gp<4;gp++){
        u32x4 u = PfA[gp];
        f32x4 p0, p1;
        p0[0] = __builtin_bit_cast(float, u[0]<<16);
        p0[1] = __builtin_bit_cast(float, u[0] & 0xffff0000u);
        p0[2] = __builtin_bit_cast(float, u[1]<<16);
        p0[3] = __builtin_bit_cast(float, u[1] & 0xffff0000u);
        p1[0] = __builtin_bit_cast(float, u[2]<<16);
        p1[1] = __builtin_bit_cast(float, u[2] & 0xffff0000u);
        p1[2] = __builtin_bit_cast(float, u[3]<<16);
        p1[3] = __builtin_bit_cast(float, u[3] & 0xffff0000u);
        s1[2*gp]   = p0 * rl[2*gp];
        s1[2*gp+1] = p1 * rl[2*gp+1];
      }
      const unsigned short* Pn = Pw + (size_t)(jt2+1)*8*64*4;
      #pragma unroll
      for(int gp=0;gp<4;gp++)
        PfB[gp] = *(const u32x4*)(Pn + ((size_t)gp*64 + lane)*8);
      const size_t jqn = (size_t)((cb + (jt2+1)*16)>>2) + q;
      #pragma unroll
      for(int g=0;g<4;g++){
        const int gh = go0*4 + g;
        const unsigned short* vb = VAb + (((size_t)gh*(NP/4) + jqn)<<8) + (m<<4);
        VfB[g][0] = *(const s16x8*)(vb);
        VfB[g][1] = *(const s16x8*)(vb + 8);
      }
      #pragma unroll
      for(int g=0;g<4;g++){
        f32x4 a = s1[0]*w2[0][g];
        #pragma unroll
        for(int h=1;h<8;h++) a += s1[h]*w2[h][g];
        s16x4 A2 = pack4(a);
        Oacc[g][0] = mfma16k16(__builtin_shufflevector(VfA[g][0], VfA[g][0], 0,1,2,3), A2, Oacc[g][0]);
        Oacc[g][1] = mfma16k16(__builtin_shufflevector(VfA[g][0], VfA[g][0], 4,5,6,7), A2, Oacc[g][1]);
        Oacc[g][2] = mfma16k16(__builtin_shufflevector(VfA[g][1], VfA[g][1], 0,1,2,3), A2, Oacc[g][2]);
        Oacc[g][3] = mfma16k16(__builtin_shufflevector(VfA[g][1], VfA[g][1], 4,5,6,7), A2, Oacc[g][3]);
      }
    }
    // ---- odd step: consume B (jt2+1), prefetch A (jt2+2 if valid) ----
    {
      f32x4 s1[8];
      #pragma unroll
      for(int gp=0;gp<4;gp++){
        u32x4 u = PfB[gp];
        f32x4 p0, p1;
        p0[0] = __builtin_bit_cast(float, u[0]<<16);
        p0[1] = __builtin_bit_cast(float, u[0] & 0xffff0000u);
        p0[2] = __builtin_bit_cast(float, u[1]<<16);
        p0[3] = __builtin_bit_cast(float, u[1] & 0xffff0000u);
        p1[0] = __builtin_bit_cast(float, u[2]<<16);
        p1[1] = __builtin_bit_cast(float, u[2] & 0xffff0000u);
        p1[2] = __builtin_bit_cast(float, u[3]<<16);
        p1[3] = __builtin_bit_cast(float, u[3] & 0xffff0000u);
        s1[2*gp]   = p0 * rl[2*gp];
        s1[2*gp+1] = p1 * rl[2*gp+1];
      }
      if(jt2+2 < NT2){
        const unsigned short* Pn = Pw + (size_t)(jt2+2)*8*64*4;
        #pragma unroll
        for(int gp=0;gp<4;gp++)
          PfA[gp] = *(const u32x4*)(Pn + ((size_t)gp*64 + lane)*8);
        const size_t jqn = (size_t)((cb + (jt2+2)*16)>>2) + q;
        #pragma unroll
        for(int g=0;g<4;g++){
          const int gh = go0*4 + g;
          const unsigned short* vb = VAb + (((size_t)gh*(NP/4) + jqn)<<8) + (m<<4);
          VfA[g][0] = *(const s16x8*)(vb);
          VfA[g][1] = *(const s16x8*)(vb + 8);
        }
      }
      #pragma unroll
      for(int g=0;g<4;g++){
        f32x4 a = s1[0]*w2[0][g];
        #pragma unroll
        for(int h=1;h<8;h++) a += s1[h]*w2[h][g];
        s16x4 A2 = pack4(a);
        Oacc[g][0] = mfma16k16(__builtin_shufflevector(VfB[g][0], VfB[g][0], 0,1,2,3), A2, Oacc[g][0]);
        Oacc[g][1] = mfma16k16(__builtin_shufflevector(VfB[g][0], VfB[g][0], 4,5,6,7), A2, Oacc[g][1]);
        Oacc[g][2] = mfma16k16(__builtin_shufflevector(VfB[g][1], VfB[g][1], 0,1,2,3), A2, Oacc[g][2]);
        Oacc[g][3] = mfma16k16(__builtin_shufflevector(VfB[g][1], VfB[g][1], 4,5,6,7), A2, Oacc[g][3]);
      }
    }
  }

  // epilogue: 32x256 slab via LDS, coalesced PLAIN stores (reduce reads next)
  #pragma unroll
  for(int g=0;g<4;g++)
    #pragma unroll
    for(int nt=0;nt<4;nt++){
      s16x4 pk = pack4(Oacc[g][nt]);
      *(s16x4*)(&Osh[(size_t)(iw*16 + m)*SPITCH + g*64 + nt*16 + 4*q]) = pk;
    }
  __syncthreads();
  unsigned short* Oc = Opart + (size_t)c*NROWS*DM;
  const size_t R0 = (size_t)b*NP + (size_t)it*32;
  const int col0 = go0*256;
  #pragma unroll
  for(int t=0;t<8;t++){
    int idx = t*128 + tid;
    int row = idx>>5, c8 = idx&31;
    u32x4 v = *(const u32x4*)(&Osh[(size_t)row*SPITCH + c8*8]);
    *(u32x4*)(Oc + (R0 + row)*DM + col0 + c8*8) = v;
  }
}

// ---------------- chunk reduction: Of = sum_c Opart_c (bf16, f32 accum) ----
__global__ __launch_bounds__(256) void reduce_kern(const unsigned short* __restrict__ Op,
    unsigned short* __restrict__ Of){
  const size_t i = ((size_t)blockIdx.x*256 + threadIdx.x)*8;
  float acc[8] = {};
  #pragma unroll
  for(int cc=0;cc<JC2;cc++){
    u32x4 v = *(const u32x4*)(Op + (size_t)cc*NROWS*DM + i);
    #pragma unroll
    for(int e=0;e<4;e++){
      unsigned u = v[e];
      acc[2*e]   += __builtin_bit_cast(float, u<<16);
      acc[2*e+1] += __builtin_bit_cast(float, u & 0xffff0000u);
    }
  }
  u32x4 o;
  #pragma unroll
  for(int e=0;e<4;e++)
    o[e] = (unsigned)f2bf(acc[2*e]) | ((unsigned)f2bf(acc[2*e+1])<<16);
  *(u32x4*)(Of + i) = o;
}

// ---------------- output projection: out = Of @ Wproj (single pass) -------
__global__ __launch_bounds__(256) void oproj_kern(const unsigned short* __restrict__ Of,
    const unsigned short* __restrict__ WT, float* __restrict__ out){
  const int nb = blockIdx.y;
  const int R0 = blockIdx.x*64;
  const int tid = threadIdx.x;
  const int w = tid>>6, lane = tid&63, m = lane&15, q = lane>>4;
  const unsigned short* Wp = WT + (size_t)3*DM*DM;
  f32x4 acc[4] = {};
  const unsigned short* brow = Wp + (size_t)(nb*64 + m)*DM + q*8;
  const unsigned short* arow = Of + (size_t)(R0 + w*16 + m)*DM + q*8;
  for(int k=0;k<DM;k+=32){
    s16x8 A = *(const s16x8*)(arow + k);
    #pragma unroll
    for(int nt=0;nt<4;nt++){
      s16x8 B = *(const s16x8*)(brow + (size_t)nt*16*DM + k);
      acc[nt] = mfma16(A, B, acc[nt]);
    }
  }
  #pragma unroll
  for(int nt=0;nt<4;nt++)
    #pragma unroll
    for(int r=0;r<4;r++)
      out[(size_t)(R0 + w*16 + q*4 + r)*DM + nb*64 + nt*16 + m] = acc[nt][r];
}

extern "C" void kernel_launch(void* const* d_in, const int* in_sizes, int n_in,
                              void* d_out, int out_size, void* d_ws, size_t ws_size,
                              hipStream_t stream){
  (void)in_sizes; (void)n_in; (void)out_size;
  const float* x  = (const float*)d_in[0];
  const float* Wq = (const float*)d_in[1];
  const float* Wk = (const float*)d_in[2];
  const float* Wv = (const float*)d_in[3];
  const float* W1 = (const float*)d_in[4];
  const float* W2 = (const float*)d_in[5];
  const float* Wp = (const float*)d_in[6];

  char* ws = (char*)d_ws;
  unsigned short* xb = (unsigned short*)ws;  ws += (size_t)NROWS*DM*2;     // 4 MB
  unsigned short* WT = (unsigned short*)ws;  ws += (size_t)4*DM*DM*2;      // 2 MB
  unsigned short* Qs = (unsigned short*)ws;  ws += (size_t)NB*NH*NP*DH*2;  // 4 MB
  unsigned short* Kk = (unsigned short*)ws;  ws += (size_t)NB*NH*NP*DH*2;  // 4 MB
  unsigned short* VA = (unsigned short*)ws;  ws += (size_t)NB*NH*DH*NP*2;  // 4 MB
  float*          Lp = (float*)ws;           ws += (size_t)JC1*NB*NH*NP*4; // 2 MB
  unsigned short* Op = (unsigned short*)ws;  ws += (size_t)JC2*NROWS*DM*2; // 32 MB
  unsigned short* Pm = (unsigned short*)ws;  // 128 MiB if it fits
  const size_t pm_bytes = (size_t)1024*2*16*8*64*4*2;  // [bx][iw][jt][g/2][lane]x8
  const size_t need = (size_t)((char*)Pm - (char*)d_ws) + pm_bytes;
  unsigned short* Of = xb;  // alias: xb is dead after qkv_kern

  prep_x<<<NROWS*DM/1024, 256, 0, stream>>>(x, xb);
  prep_w<<<dim3(8,8,4), 256, 0, stream>>>(Wq, Wk, Wv, Wp, WT);
  qkv_kern<<<dim3(64,8,3), 256, 0, stream>>>(xb, WT, Qs, Kk, VA);
  if(ws_size >= need){
    attn1p_kern<<<dim3(1024), 128, 0, stream>>>(Qs, Kk, W1, Lp, Pm);
    attn2p_kern<<<dim3(1024,2), 128, 0, stream>>>(Pm, VA, W2, Lp, Op);
  } else {
    attn1_kern<<<dim3(1024), 128, 0, stream>>>(Qs, Kk, W1, Lp);
    attn2_kern<<<dim3(1024), 128, 0, stream>>>(Qs, Kk, VA, W1, W2, Lp, Op);
  }
  reduce_kern<<<dim3(NROWS*DM/2048), 256, 0, stream>>>(Op, Of);
  oproj_kern<<<dim3(64,8), 256, 0, stream>>>(Of, WT, (float*)d_out);
}